// Round 2
// baseline (908.988 us; speedup 1.0000x reference)
//
#include <hip/hip_runtime.h>

typedef _Float16 half8 __attribute__((ext_vector_type(8)));
typedef _Float16 half4v __attribute__((ext_vector_type(4)));
typedef float floatx4 __attribute__((ext_vector_type(4)));
typedef unsigned int uintx4 __attribute__((ext_vector_type(4)));

#define GLDS16(gsrc, ldst)                                                                  \
  __builtin_amdgcn_global_load_lds((const __attribute__((address_space(1))) void*)(gsrc),   \
                                   (__attribute__((address_space(3))) void*)(ldst), 16, 0, 0)
#define MFMA16(a, b, c) __builtin_amdgcn_mfma_f32_16x16x32_f16(a, b, c, 0, 0, 0)

static __device__ __forceinline__ float fast_exp2(float x) {
#if __has_builtin(__builtin_amdgcn_exp2f)
  return __builtin_amdgcn_exp2f(x);
#else
  return exp2f(x);
#endif
}
static __device__ __forceinline__ int pk2(float a, float b) {
  return __builtin_bit_cast(int, __builtin_amdgcn_cvt_pkrtz(a, b));
}

// ------------------------------------------------------------------
// fp32 -> fp16 convert, 8 elems/thread
// ------------------------------------------------------------------
__global__ __launch_bounds__(256) void cvt_f32_f16(const float* __restrict__ src,
                                                   _Float16* __restrict__ dst, int n8) {
  int i = blockIdx.x * 256 + threadIdx.x;
  if (i >= n8) return;
  const float4* s4 = (const float4*)src;
  float4 a = s4[2 * (size_t)i];
  float4 b = s4[2 * (size_t)i + 1];
  half8 h;
  h[0] = (_Float16)a.x; h[1] = (_Float16)a.y; h[2] = (_Float16)a.z; h[3] = (_Float16)a.w;
  h[4] = (_Float16)b.x; h[5] = (_Float16)b.y; h[6] = (_Float16)b.z; h[7] = (_Float16)b.w;
  *(half8*)(dst + 8 * (size_t)i) = h;
}

// ------------------------------------------------------------------
// NT GEMM: C[M,N] = A[M,K] @ W[N,K]^T + bias. (unchanged structure from R1)
// mode 1: fused qkv epilogue: bias + RoPE + q-prescale (1/sqrt(D)*log2e).
// ------------------------------------------------------------------
__global__ __launch_bounds__(256) void gemm_nt(
    const _Float16* __restrict__ A, const _Float16* __restrict__ W,
    const float* __restrict__ bias, float* __restrict__ C,
    int M, int N, int K, int mode,
    _Float16* __restrict__ qfp, _Float16* __restrict__ kfp, _Float16* __restrict__ vfp) {
  __shared__ __align__(16) _Float16 As[128 * 32];
  __shared__ __align__(16) _Float16 Bs[128 * 32];
  const int tid = threadIdx.x;
  const int wave = tid >> 6, lane = tid & 63;
  const int wr = wave >> 1, wc = wave & 1;
  const int g = lane >> 4, r16 = lane & 15;
  const int m0 = blockIdx.y * 128, n0 = blockIdx.x * 128;

  const int c0 = wave * 2;
  const int srow0 = c0 * 16 + (lane >> 2);
  const int srow1 = srow0 + 16;
  const int sl = lane & 3;
  const _Float16* pa0 = A + (size_t)(m0 + srow0) * K + ((sl ^ ((srow0 >> 1) & 3)) << 3);
  const _Float16* pa1 = A + (size_t)(m0 + srow1) * K + ((sl ^ ((srow1 >> 1) & 3)) << 3);
  const _Float16* pw0 = W + (size_t)(n0 + srow0) * K + ((sl ^ ((srow0 >> 1) & 3)) << 3);
  const _Float16* pw1 = W + (size_t)(n0 + srow1) * K + ((sl ^ ((srow1 >> 1) & 3)) << 3);
  _Float16* da0 = As + c0 * 512;
  _Float16* da1 = As + c0 * 512 + 512;
  _Float16* db0 = Bs + c0 * 512;
  _Float16* db1 = Bs + c0 * 512 + 512;

  floatx4 acc[4][4] = {};

  for (int k0 = 0; k0 < K; k0 += 32) {
    __syncthreads();
    GLDS16(pa0 + k0, da0);
    GLDS16(pa1 + k0, da1);
    GLDS16(pw0 + k0, db0);
    GLDS16(pw1 + k0, db1);
    __syncthreads();
    half8 af[4], bf[4];
#pragma unroll
    for (int m = 0; m < 4; ++m) {
      int row = wr * 64 + m * 16 + r16;
      af[m] = *(const half8*)(As + row * 32 + ((g ^ ((row >> 1) & 3)) << 3));
    }
#pragma unroll
    for (int n = 0; n < 4; ++n) {
      int row = wc * 64 + n * 16 + r16;
      bf[n] = *(const half8*)(Bs + row * 32 + ((g ^ ((row >> 1) & 3)) << 3));
    }
#pragma unroll
    for (int m = 0; m < 4; ++m)
#pragma unroll
      for (int n = 0; n < 4; ++n)
        acc[m][n] = MFMA16(af[m], bf[n], acc[m][n]);
  }

  if (mode == 0) {
#pragma unroll
    for (int m = 0; m < 4; ++m)
#pragma unroll
      for (int ri = 0; ri < 4; ++ri) {
        int row = m0 + wr * 64 + m * 16 + g * 4 + ri;
#pragma unroll
        for (int n = 0; n < 4; ++n) {
          int col = n0 + wc * 64 + n * 16 + r16;
          C[(size_t)row * N + col] = acc[m][n][ri] + bias[col];
        }
      }
  } else {
    const int bx = blockIdx.x;
    const int h = bx / 3, s = bx % 3;
    _Float16* dst = (s == 0) ? qfp : (s == 1 ? kfp : vfp);
    const float theta = exp2f(-(float)r16 * 0.83048202372184058f);
#pragma unroll
    for (int m = 0; m < 4; ++m)
#pragma unroll
      for (int ri = 0; ri < 4; ++ri) {
        int t = m0 + wr * 64 + m * 16 + g * 4 + ri;
        float v[4];
#pragma unroll
        for (int n = 0; n < 4; ++n)
          v[n] = acc[m][n][ri] + bias[n0 + wc * 64 + n * 16 + r16];
        if (s < 2 && wc == 0) {
          float sn, cs;
          sincosf((float)t * theta, &sn, &cs);
          float a0 = v[0], a1 = v[1];
          v[0] = a0 * cs - a1 * sn;
          v[1] = a1 * cs + a0 * sn;
        }
        if (s == 0) {
          // fold softmax scale (1/sqrt(128)) * log2(e) into q
#pragma unroll
          for (int n = 0; n < 4; ++n) v[n] *= 0.12751744f;
        }
        size_t rb = ((size_t)h * 2048 + t) * 128 + wc * 64 + r16;
#pragma unroll
        for (int n = 0; n < 4; ++n) dst[rb + n * 16] = (_Float16)v[n];
      }
  }
}

// ------------------------------------------------------------------
// V [H][T][D] f16 -> V^T [H][D][T] f16, 64x64 tiles through LDS.
// ------------------------------------------------------------------
__global__ __launch_bounds__(256) void transpose_v(const _Float16* __restrict__ src,
                                                   _Float16* __restrict__ dst) {
  __shared__ __align__(16) _Float16 tile[64][72];
  const int h = blockIdx.z, tb = blockIdx.y, db = blockIdx.x;
  const int t0 = tb * 64, d0 = db * 64;
  const int r = threadIdx.x >> 2, a = threadIdx.x & 3;
  const _Float16* s = src + ((size_t)h * 2048 + t0 + r) * 128 + d0 + a * 16;
  *(half8*)&tile[r][a * 16] = *(const half8*)s;
  *(half8*)&tile[r][a * 16 + 8] = *(const half8*)(s + 8);
  __syncthreads();
  half8 o0, o1;
#pragma unroll
  for (int e = 0; e < 8; ++e) o0[e] = tile[a * 16 + e][r];
#pragma unroll
  for (int e = 0; e < 8; ++e) o1[e] = tile[a * 16 + 8 + e][r];
  _Float16* dp = dst + ((size_t)h * 128 + d0 + r) * 2048 + t0 + a * 16;
  *(half8*)dp = o0;
  *(half8*)(dp + 8) = o1;
}

// ------------------------------------------------------------------
// Flash attention, causal, LDS-free / barrier-free.
// 512 blocks (h = bid&31 -> XCD-affine), 4 waves x 32 q-rows, KVBLK=64.
// Swapped QK^T: S^T = mfma(K, Q) -> lane-local softmax rows (q = lane&15).
// PV: O^T = mfma(V^T, P^T); V^T frags read directly from global [H][D][T].
// Q pre-scaled by 1/sqrt(D)*log2e in gemm epilogue -> exp2-domain softmax.
// Defer-rescale threshold 2.0 (P <= 4, f16-safe).
// ------------------------------------------------------------------
__global__ __launch_bounds__(256, 2) void attn(const _Float16* __restrict__ qf,
                                               const _Float16* __restrict__ kf,
                                               const _Float16* __restrict__ vt,
                                               _Float16* __restrict__ yf) {
  const int bid = blockIdx.x;
  const int halfsel = bid >> 8, idx = bid & 255;
  const int h = idx & 31, qb = idx >> 5;
  const int qt = halfsel ? qb : 15 - qb;  // pair long/short tiles per CU
  const int lane = threadIdx.x & 63, wave = threadIdx.x >> 6;
  const int g = lane >> 4, r16 = lane & 15;
  const int q0 = qt * 128 + wave * 32;
  const _Float16* qh = qf + (size_t)h * (2048 * 128);
  const _Float16* kh = kf + (size_t)h * (2048 * 128);
  const _Float16* vh = vt + (size_t)h * (128 * 2048);

  // Q as B-operand: col = r16 (q-row), k = g*8+j within each 32-d chunk
  half8 qfr[2][4];
#pragma unroll
  for (int i = 0; i < 2; ++i)
#pragma unroll
    for (int kk = 0; kk < 4; ++kk)
      qfr[i][kk] = *(const half8*)(qh + (size_t)(q0 + i * 16 + r16) * 128 + kk * 32 + g * 8);

  floatx4 O[8][2] = {};  // O^T frags: [d-chunk n][q-frag i]
  float m[2] = {-1e30f, -1e30f}, l[2] = {0.f, 0.f};
  const int nkt = (q0 >> 6) + 1;

  for (int kt = 0; kt < nkt; ++kt) {
    const int k0 = kt * 64;

    // --- S^T = K @ Q : S[j][i] covers keys j*16+(g*4+r), q = i*16+r16 ---
    floatx4 S[4][2] = {};
#pragma unroll
    for (int j = 0; j < 4; ++j) {
      const _Float16* kp = kh + (size_t)(k0 + j * 16 + r16) * 128 + g * 8;
      half8 k0f = *(const half8*)(kp);
      half8 k1f = *(const half8*)(kp + 32);
      half8 k2f = *(const half8*)(kp + 64);
      half8 k3f = *(const half8*)(kp + 96);
      S[j][0] = MFMA16(k0f, qfr[0][0], S[j][0]);
      S[j][1] = MFMA16(k0f, qfr[1][0], S[j][1]);
      S[j][0] = MFMA16(k1f, qfr[0][1], S[j][0]);
      S[j][1] = MFMA16(k1f, qfr[1][1], S[j][1]);
      S[j][0] = MFMA16(k2f, qfr[0][2], S[j][0]);
      S[j][1] = MFMA16(k2f, qfr[1][2], S[j][1]);
      S[j][0] = MFMA16(k3f, qfr[0][3], S[j][0]);
      S[j][1] = MFMA16(k3f, qfr[1][3], S[j][1]);
    }

    // --- causal mask (only the final tile can cross the diagonal) ---
    if (kt == nkt - 1) {
#pragma unroll
      for (int j = 0; j < 4; ++j)
#pragma unroll
        for (int r = 0; r < 4; ++r) {
          int key = k0 + j * 16 + g * 4 + r;
#pragma unroll
          for (int i = 0; i < 2; ++i)
            if (key > q0 + i * 16 + r16) S[j][i][r] = -1e30f;
        }
    }

    // --- row max: in-lane over 16 values + cross-g (xor 16/32) ---
    float rm[2];
#pragma unroll
    for (int i = 0; i < 2; ++i) {
      float a0 = fmaxf(fmaxf(S[0][i][0], S[0][i][1]), fmaxf(S[0][i][2], S[0][i][3]));
      float a1 = fmaxf(fmaxf(S[1][i][0], S[1][i][1]), fmaxf(S[1][i][2], S[1][i][3]));
      float a2 = fmaxf(fmaxf(S[2][i][0], S[2][i][1]), fmaxf(S[2][i][2], S[2][i][3]));
      float a3 = fmaxf(fmaxf(S[3][i][0], S[3][i][1]), fmaxf(S[3][i][2], S[3][i][3]));
      float a = fmaxf(fmaxf(a0, a1), fmaxf(a2, a3));
      a = fmaxf(a, __shfl_xor(a, 16));
      a = fmaxf(a, __shfl_xor(a, 32));
      rm[i] = a;
    }

    // --- deferred rescale: only when some row's max grew by > 2 (log2) ---
    if (__any((rm[0] > m[0] + 2.0f) || (rm[1] > m[1] + 2.0f))) {
#pragma unroll
      for (int i = 0; i < 2; ++i) {
        float mn = fmaxf(m[i], rm[i]);
        float corr = fast_exp2(m[i] - mn);
        m[i] = mn;
        l[i] *= corr;
#pragma unroll
        for (int n = 0; n < 8; ++n) O[n][i] = O[n][i] * corr;
      }
    }

    // --- p = exp2(S - m); row sum ---
#pragma unroll
    for (int i = 0; i < 2; ++i) {
      float s = 0.f;
#pragma unroll
      for (int j = 0; j < 4; ++j)
#pragma unroll
        for (int r = 0; r < 4; ++r) {
          float p = fast_exp2(S[j][i][r] - m[i]);
          S[j][i][r] = p;
          s += p;
        }
      s += __shfl_xor(s, 16);
      s += __shfl_xor(s, 32);
      l[i] += s;
    }

    // --- O^T += V^T @ P^T, per 32-key chunk ---
#pragma unroll
    for (int c = 0; c < 2; ++c) {
      half8 pb[2];
#pragma unroll
      for (int i = 0; i < 2; ++i) {
        // pack p to f16 pairs, then redistribute across g-groups:
        // B-frag word w of dest lane g <- packed words of lanes (g&1)*32+{0,16}+r16
        int s0 = pk2(S[2 * c][i][0], S[2 * c][i][1]);
        int s1 = pk2(S[2 * c][i][2], S[2 * c][i][3]);
        int s2 = pk2(S[2 * c + 1][i][0], S[2 * c + 1][i][1]);
        int s3 = pk2(S[2 * c + 1][i][2], S[2 * c + 1][i][3]);
        int la = ((g & 1) << 5) + r16;
        int lb = la + 16;
        int t0a = __shfl(s0, la), t2a = __shfl(s2, la);
        int t1a = __shfl(s1, la), t3a = __shfl(s3, la);
        int t0b = __shfl(s0, lb), t2b = __shfl(s2, lb);
        int t1b = __shfl(s1, lb), t3b = __shfl(s3, lb);
        uintx4 w;
        w[0] = (g < 2) ? (unsigned)t0a : (unsigned)t2a;
        w[1] = (g < 2) ? (unsigned)t1a : (unsigned)t3a;
        w[2] = (g < 2) ? (unsigned)t0b : (unsigned)t2b;
        w[3] = (g < 2) ? (unsigned)t1b : (unsigned)t3b;
        pb[i] = __builtin_bit_cast(half8, w);
      }
      const _Float16* vp = vh + (size_t)r16 * 2048 + k0 + c * 32 + g * 8;
#pragma unroll
      for (int n = 0; n < 8; ++n) {
        half8 va = *(const half8*)(vp + (size_t)n * (16 * 2048));
        O[n][0] = MFMA16(va, pb[0], O[n][0]);
        O[n][1] = MFMA16(va, pb[1], O[n][1]);
      }
    }
  }

  // --- epilogue: y[t][h*128+d] f16, d = n*16+g*4+r ---
#pragma unroll
  for (int i = 0; i < 2; ++i) {
    float inv = 1.0f / l[i];
    size_t rb = (size_t)(q0 + i * 16 + r16) * 4096 + h * 128 + g * 4;
#pragma unroll
    for (int n = 0; n < 8; ++n) {
      half4v o;
      o[0] = (_Float16)(O[n][i][0] * inv);
      o[1] = (_Float16)(O[n][i][1] * inv);
      o[2] = (_Float16)(O[n][i][2] * inv);
      o[3] = (_Float16)(O[n][i][3] * inv);
      *(half4v*)(yf + rb + n * 16) = o;
    }
  }
}

// ------------------------------------------------------------------
extern "C" void kernel_launch(void* const* d_in, const int* in_sizes, int n_in,
                              void* d_out, int out_size, void* d_ws, size_t ws_size,
                              hipStream_t stream) {
  const float* x = (const float*)d_in[0];
  const float* w_attn = (const float*)d_in[1];
  const float* b_attn = (const float*)d_in[2];
  const float* w_proj = (const float*)d_in[3];
  const float* b_proj = (const float*)d_in[4];
  float* out = (float*)d_out;

  _Float16* xh = (_Float16*)d_ws;
  _Float16* wa = xh + (size_t)2048 * 4096;
  _Float16* wp = wa + (size_t)12288 * 4096;
  _Float16* qfp = wp + (size_t)4096 * 4096;
  _Float16* kfp = qfp + (size_t)32 * 2048 * 128;
  _Float16* vfp = kfp + (size_t)32 * 2048 * 128;
  _Float16* yf = vfp + (size_t)32 * 2048 * 128;
  _Float16* vtp = xh;  // alias: xh dead after qkv GEMM, sizes match exactly

  cvt_f32_f16<<<(2048 * 4096 / 8 + 255) / 256, 256, 0, stream>>>(x, xh, 2048 * 4096 / 8);
  cvt_f32_f16<<<(12288 * 4096 / 8 + 255) / 256, 256, 0, stream>>>(w_attn, wa, 12288 * 4096 / 8);
  cvt_f32_f16<<<(4096 * 4096 / 8 + 255) / 256, 256, 0, stream>>>(w_proj, wp, 4096 * 4096 / 8);

  gemm_nt<<<dim3(96, 16), 256, 0, stream>>>(xh, wa, b_attn, nullptr, 2048, 12288, 4096, 1,
                                            qfp, kfp, vfp);
  transpose_v<<<dim3(2, 32, 32), 256, 0, stream>>>(vfp, vtp);
  attn<<<512, 256, 0, stream>>>(qfp, kfp, vtp, yf);
  gemm_nt<<<dim3(32, 16), 256, 0, stream>>>(yf, wp, b_proj, out, 2048, 4096, 4096, 0,
                                            nullptr, nullptr, nullptr);
}

// Round 3
// 899.825 us; speedup vs baseline: 1.0102x; 1.0102x over previous
//
#include <hip/hip_runtime.h>

typedef _Float16 half8 __attribute__((ext_vector_type(8)));
typedef _Float16 half4v __attribute__((ext_vector_type(4)));
typedef float floatx4 __attribute__((ext_vector_type(4)));
typedef unsigned int uintx4 __attribute__((ext_vector_type(4)));

#define GLDS16(gsrc, ldst)                                                                  \
  __builtin_amdgcn_global_load_lds((const __attribute__((address_space(1))) void*)(gsrc),   \
                                   (__attribute__((address_space(3))) void*)(ldst), 16, 0, 0)
#define MFMA16(a, b, c) __builtin_amdgcn_mfma_f32_16x16x32_f16(a, b, c, 0, 0, 0)

static __device__ __forceinline__ float fast_exp2(float x) {
#if __has_builtin(__builtin_amdgcn_exp2f)
  return __builtin_amdgcn_exp2f(x);
#else
  return exp2f(x);
#endif
}
static __device__ __forceinline__ int pk2(float a, float b) {
  return __builtin_bit_cast(int, __builtin_amdgcn_cvt_pkrtz(a, b));
}

// ------------------------------------------------------------------
// fp32 -> fp16 convert, 8 elems/thread
// ------------------------------------------------------------------
__global__ __launch_bounds__(256) void cvt_f32_f16(const float* __restrict__ src,
                                                   _Float16* __restrict__ dst, int n8) {
  int i = blockIdx.x * 256 + threadIdx.x;
  if (i >= n8) return;
  const float4* s4 = (const float4*)src;
  float4 a = s4[2 * (size_t)i];
  float4 b = s4[2 * (size_t)i + 1];
  half8 h;
  h[0] = (_Float16)a.x; h[1] = (_Float16)a.y; h[2] = (_Float16)a.z; h[3] = (_Float16)a.w;
  h[4] = (_Float16)b.x; h[5] = (_Float16)b.y; h[6] = (_Float16)b.z; h[7] = (_Float16)b.w;
  *(half8*)(dst + 8 * (size_t)i) = h;
}

// ------------------------------------------------------------------
// NT GEMM, 256x256 tile, BK=32, 8 waves (2Mx4N, per-wave 128x64 = acc[8][4]).
// Deep pipeline: 4-slot LDS K-tile ring (128KB), staging 2 tiles ahead via
// global_load_lds(16B, both-sides XOR swizzle), counted vmcnt(4) at tile ends,
// 2 phases/tile x 16 MFMA, setprio around MFMA, sched_barrier-pinned s_barrier.
// mode 0: C fp32 + bias. mode 1: qkv epilogue (bias + RoPE + q prescale).
// ------------------------------------------------------------------
__global__ __launch_bounds__(512, 2) void gemm_nt(
    const _Float16* __restrict__ A, const _Float16* __restrict__ W,
    const float* __restrict__ bias, float* __restrict__ C,
    int M, int N, int K, int mode,
    _Float16* __restrict__ qfp, _Float16* __restrict__ kfp, _Float16* __restrict__ vfp) {
  __shared__ __align__(16) _Float16 lds[65536];  // A: [0,32768), B: [32768,65536)
  const int tid = threadIdx.x;
  const int w = tid >> 6, lane = tid & 63;
  const int wm = w >> 2, wn = w & 3;
  const int g = lane >> 4, r16 = lane & 15;
  const int gx = gridDim.x;
  const int nwg = gx * gridDim.y;
  const int flat = blockIdx.y * gx + blockIdx.x;
  const int swz = (flat & 7) * (nwg >> 3) + (flat >> 3);  // nwg % 8 == 0 for our grids
  const int tn = swz % gx, tm = swz / gx;
  const int m0 = tm * 256, n0 = tn * 256;
  const int NT = K >> 5;

  // staging geometry: per thread 1 load per half (128 rows); 2 halves per operand
  const int s_row = w * 16 + (lane >> 2);                     // 0..127
  const int s_col = (((lane & 3) ^ ((s_row >> 1) & 3)) << 3); // swizzled src col (halfs)
  const _Float16* pa0 = A + (size_t)(m0 + s_row) * K + s_col;
  const _Float16* pa1 = A + (size_t)(m0 + 128 + s_row) * K + s_col;
  const _Float16* pw0 = W + (size_t)(n0 + s_row) * K + s_col;
  const _Float16* pw1 = W + (size_t)(n0 + 128 + s_row) * K + s_col;
  const int dH0 = w * 512;          // LDS dest base (halfs), li=0
  const int dH1 = 4096 + w * 512;   // li=1

#define STAGE_A(t)                                        \
  {                                                       \
    const int sb = ((t) & 3) * 8192;                      \
    const int k0s = (t) << 5;                             \
    GLDS16(pa0 + k0s, &lds[sb + dH0]);                    \
    GLDS16(pa1 + k0s, &lds[sb + dH1]);                    \
  }
#define STAGE_B(t)                                        \
  {                                                       \
    const int sb = 32768 + (((t) & 3) * 8192);            \
    const int k0s = (t) << 5;                             \
    GLDS16(pw0 + k0s, &lds[sb + dH0]);                    \
    GLDS16(pw1 + k0s, &lds[sb + dH1]);                    \
  }

  floatx4 acc[8][4] = {};
  half8 af[8], bf[2];

  // prologue: stage tiles 0 and 1; tile 0's 4 loads are oldest -> vmcnt(4)
  STAGE_A(0); STAGE_B(0);
  STAGE_A(1); STAGE_B(1);
  asm volatile("s_waitcnt vmcnt(4)" ::: "memory");
  __builtin_amdgcn_s_barrier();

  for (int t = 0; t < NT; ++t) {
    const int abase = (t & 3) * 8192;
    // ---- phase 0: read A frags (held for both phases) + B(nq=0); stage A(t+2)
#pragma unroll
    for (int fm = 0; fm < 8; ++fm) {
      int arow = wm * 128 + fm * 16 + r16;
      af[fm] = *(const half8*)&lds[abase + arow * 32 + ((g ^ ((arow >> 1) & 3)) << 3)];
    }
#pragma unroll
    for (int fn = 0; fn < 2; ++fn) {
      int bcol = wn * 64 + fn * 16 + r16;
      bf[fn] = *(const half8*)&lds[32768 + abase + bcol * 32 + ((g ^ ((bcol >> 1) & 3)) << 3)];
    }
    if (t + 2 < NT) STAGE_A(t + 2);
    __builtin_amdgcn_s_barrier();
    __builtin_amdgcn_sched_barrier(0);
    __builtin_amdgcn_s_setprio(1);
#pragma unroll
    for (int fm = 0; fm < 8; ++fm) {
      acc[fm][0] = MFMA16(af[fm], bf[0], acc[fm][0]);
      acc[fm][1] = MFMA16(af[fm], bf[1], acc[fm][1]);
    }
    __builtin_amdgcn_s_setprio(0);
    __builtin_amdgcn_sched_barrier(0);
    __builtin_amdgcn_s_barrier();

    // ---- phase 1: read B(nq=1); stage B(t+2)
#pragma unroll
    for (int fn = 0; fn < 2; ++fn) {
      int bcol = wn * 64 + 32 + fn * 16 + r16;
      bf[fn] = *(const half8*)&lds[32768 + abase + bcol * 32 + ((g ^ ((bcol >> 1) & 3)) << 3)];
    }
    if (t + 2 < NT) STAGE_B(t + 2);
    __builtin_amdgcn_s_barrier();
    __builtin_amdgcn_sched_barrier(0);
    __builtin_amdgcn_s_setprio(1);
#pragma unroll
    for (int fm = 0; fm < 8; ++fm) {
      acc[fm][2] = MFMA16(af[fm], bf[0], acc[fm][2]);
      acc[fm][3] = MFMA16(af[fm], bf[1], acc[fm][3]);
    }
    __builtin_amdgcn_s_setprio(0);
    // tile-end wait: tile t+1's 4 loads (issued during t-1) must retire.
    // steady state: outstanding <= 8, counted drain to 4. tail: drain fully once.
    if (t == NT - 2)
      asm volatile("s_waitcnt vmcnt(0)" ::: "memory");
    else
      asm volatile("s_waitcnt vmcnt(4)" ::: "memory");
    __builtin_amdgcn_sched_barrier(0);
    __builtin_amdgcn_s_barrier();
  }

#undef STAGE_A
#undef STAGE_B

  // ---- epilogue: C layout row=(lane>>4)*4+ri, col=lane&15 per 16x16 frag
  if (mode == 0) {
#pragma unroll
    for (int fm = 0; fm < 8; ++fm)
#pragma unroll
      for (int ri = 0; ri < 4; ++ri) {
        int row = m0 + wm * 128 + fm * 16 + g * 4 + ri;
#pragma unroll
        for (int j = 0; j < 4; ++j) {
          int col = n0 + wn * 64 + j * 16 + r16;
          C[(size_t)row * N + col] = acc[fm][j][ri] + bias[col];
        }
      }
  } else {
    // qkv column group: gc = col>>7 uniform per wave; c = h*384 + s*128 + d
    const int gc = (n0 + wn * 64) >> 7;
    const int h = gc / 3, s = gc - 3 * h;
    _Float16* dst = (s == 0) ? qfp : (s == 1 ? kfp : vfp);
    const float theta = exp2f(-(float)r16 * 0.83048202372184058f);
    const bool dorope = (s < 2) && ((wn & 1) == 0);
#pragma unroll
    for (int fm = 0; fm < 8; ++fm)
#pragma unroll
      for (int ri = 0; ri < 4; ++ri) {
        int tt = m0 + wm * 128 + fm * 16 + g * 4 + ri;
        float v[4];
#pragma unroll
        for (int j = 0; j < 4; ++j)
          v[j] = acc[fm][j][ri] + bias[n0 + wn * 64 + j * 16 + r16];
        if (dorope) {
          // d = j*16 + r16: j=0 -> x1 (d<16), j=1 -> x2 (16<=d<32), angle i=r16
          float sn, cs;
          sincosf((float)tt * theta, &sn, &cs);
          float a0 = v[0], a1 = v[1];
          v[0] = a0 * cs - a1 * sn;
          v[1] = a1 * cs + a0 * sn;
        }
        if (s == 0) {
#pragma unroll
          for (int j = 0; j < 4; ++j) v[j] *= 0.12751744f;  // 1/sqrt(128)*log2(e)
        }
        size_t rb = ((size_t)h * 2048 + tt) * 128 + (wn & 1) * 64 + r16;
#pragma unroll
        for (int j = 0; j < 4; ++j) dst[rb + j * 16] = (_Float16)v[j];
      }
  }
}

// ------------------------------------------------------------------
// V [H][T][D] f16 -> V^T [H][D][T] f16, 64x64 tiles through LDS.
// ------------------------------------------------------------------
__global__ __launch_bounds__(256) void transpose_v(const _Float16* __restrict__ src,
                                                   _Float16* __restrict__ dst) {
  __shared__ __align__(16) _Float16 tile[64][72];
  const int h = blockIdx.z, tb = blockIdx.y, db = blockIdx.x;
  const int t0 = tb * 64, d0 = db * 64;
  const int r = threadIdx.x >> 2, a = threadIdx.x & 3;
  const _Float16* s = src + ((size_t)h * 2048 + t0 + r) * 128 + d0 + a * 16;
  *(half8*)&tile[r][a * 16] = *(const half8*)s;
  *(half8*)&tile[r][a * 16 + 8] = *(const half8*)(s + 8);
  __syncthreads();
  half8 o0, o1;
#pragma unroll
  for (int e = 0; e < 8; ++e) o0[e] = tile[a * 16 + e][r];
#pragma unroll
  for (int e = 0; e < 8; ++e) o1[e] = tile[a * 16 + 8 + e][r];
  _Float16* dp = dst + ((size_t)h * 128 + d0 + r) * 2048 + t0 + a * 16;
  *(half8*)dp = o0;
  *(half8*)(dp + 8) = o1;
}

// ------------------------------------------------------------------
// Flash attention (UNCHANGED from R2 — clean A/B; counters surface next round)
// ------------------------------------------------------------------
__global__ __launch_bounds__(256, 2) void attn(const _Float16* __restrict__ qf,
                                               const _Float16* __restrict__ kf,
                                               const _Float16* __restrict__ vt,
                                               _Float16* __restrict__ yf) {
  const int bid = blockIdx.x;
  const int halfsel = bid >> 8, idx = bid & 255;
  const int h = idx & 31, qb = idx >> 5;
  const int qt = halfsel ? qb : 15 - qb;
  const int lane = threadIdx.x & 63, wave = threadIdx.x >> 6;
  const int g = lane >> 4, r16 = lane & 15;
  const int q0 = qt * 128 + wave * 32;
  const _Float16* qh = qf + (size_t)h * (2048 * 128);
  const _Float16* kh = kf + (size_t)h * (2048 * 128);
  const _Float16* vh = vt + (size_t)h * (128 * 2048);

  half8 qfr[2][4];
#pragma unroll
  for (int i = 0; i < 2; ++i)
#pragma unroll
    for (int kk = 0; kk < 4; ++kk)
      qfr[i][kk] = *(const half8*)(qh + (size_t)(q0 + i * 16 + r16) * 128 + kk * 32 + g * 8);

  floatx4 O[8][2] = {};
  float m[2] = {-1e30f, -1e30f}, l[2] = {0.f, 0.f};
  const int nkt = (q0 >> 6) + 1;

  for (int kt = 0; kt < nkt; ++kt) {
    const int k0 = kt * 64;
    floatx4 S[4][2] = {};
#pragma unroll
    for (int j = 0; j < 4; ++j) {
      const _Float16* kp = kh + (size_t)(k0 + j * 16 + r16) * 128 + g * 8;
      half8 k0f = *(const half8*)(kp);
      half8 k1f = *(const half8*)(kp + 32);
      half8 k2f = *(const half8*)(kp + 64);
      half8 k3f = *(const half8*)(kp + 96);
      S[j][0] = MFMA16(k0f, qfr[0][0], S[j][0]);
      S[j][1] = MFMA16(k0f, qfr[1][0], S[j][1]);
      S[j][0] = MFMA16(k1f, qfr[0][1], S[j][0]);
      S[j][1] = MFMA16(k1f, qfr[1][1], S[j][1]);
      S[j][0] = MFMA16(k2f, qfr[0][2], S[j][0]);
      S[j][1] = MFMA16(k2f, qfr[1][2], S[j][1]);
      S[j][0] = MFMA16(k3f, qfr[0][3], S[j][0]);
      S[j][1] = MFMA16(k3f, qfr[1][3], S[j][1]);
    }

    if (kt == nkt - 1) {
#pragma unroll
      for (int j = 0; j < 4; ++j)
#pragma unroll
        for (int r = 0; r < 4; ++r) {
          int key = k0 + j * 16 + g * 4 + r;
#pragma unroll
          for (int i = 0; i < 2; ++i)
            if (key > q0 + i * 16 + r16) S[j][i][r] = -1e30f;
        }
    }

    float rm[2];
#pragma unroll
    for (int i = 0; i < 2; ++i) {
      float a0 = fmaxf(fmaxf(S[0][i][0], S[0][i][1]), fmaxf(S[0][i][2], S[0][i][3]));
      float a1 = fmaxf(fmaxf(S[1][i][0], S[1][i][1]), fmaxf(S[1][i][2], S[1][i][3]));
      float a2 = fmaxf(fmaxf(S[2][i][0], S[2][i][1]), fmaxf(S[2][i][2], S[2][i][3]));
      float a3 = fmaxf(fmaxf(S[3][i][0], S[3][i][1]), fmaxf(S[3][i][2], S[3][i][3]));
      float a = fmaxf(fmaxf(a0, a1), fmaxf(a2, a3));
      a = fmaxf(a, __shfl_xor(a, 16));
      a = fmaxf(a, __shfl_xor(a, 32));
      rm[i] = a;
    }

    if (__any((rm[0] > m[0] + 2.0f) || (rm[1] > m[1] + 2.0f))) {
#pragma unroll
      for (int i = 0; i < 2; ++i) {
        float mn = fmaxf(m[i], rm[i]);
        float corr = fast_exp2(m[i] - mn);
        m[i] = mn;
        l[i] *= corr;
#pragma unroll
        for (int n = 0; n < 8; ++n) O[n][i] = O[n][i] * corr;
      }
    }

#pragma unroll
    for (int i = 0; i < 2; ++i) {
      float s = 0.f;
#pragma unroll
      for (int j = 0; j < 4; ++j)
#pragma unroll
        for (int r = 0; r < 4; ++r) {
          float p = fast_exp2(S[j][i][r] - m[i]);
          S[j][i][r] = p;
          s += p;
        }
      s += __shfl_xor(s, 16);
      s += __shfl_xor(s, 32);
      l[i] += s;
    }

#pragma unroll
    for (int c = 0; c < 2; ++c) {
      half8 pb[2];
#pragma unroll
      for (int i = 0; i < 2; ++i) {
        int s0 = pk2(S[2 * c][i][0], S[2 * c][i][1]);
        int s1 = pk2(S[2 * c][i][2], S[2 * c][i][3]);
        int s2 = pk2(S[2 * c + 1][i][0], S[2 * c + 1][i][1]);
        int s3 = pk2(S[2 * c + 1][i][2], S[2 * c + 1][i][3]);
        int la = ((g & 1) << 5) + r16;
        int lb = la + 16;
        int t0a = __shfl(s0, la), t2a = __shfl(s2, la);
        int t1a = __shfl(s1, la), t3a = __shfl(s3, la);
        int t0b = __shfl(s0, lb), t2b = __shfl(s2, lb);
        int t1b = __shfl(s1, lb), t3b = __shfl(s3, lb);
        uintx4 wv;
        wv[0] = (g < 2) ? (unsigned)t0a : (unsigned)t2a;
        wv[1] = (g < 2) ? (unsigned)t1a : (unsigned)t3a;
        wv[2] = (g < 2) ? (unsigned)t0b : (unsigned)t2b;
        wv[3] = (g < 2) ? (unsigned)t1b : (unsigned)t3b;
        pb[i] = __builtin_bit_cast(half8, wv);
      }
      const _Float16* vp = vh + (size_t)r16 * 2048 + k0 + c * 32 + g * 8;
#pragma unroll
      for (int n = 0; n < 8; ++n) {
        half8 va = *(const half8*)(vp + (size_t)n * (16 * 2048));
        O[n][0] = MFMA16(va, pb[0], O[n][0]);
        O[n][1] = MFMA16(va, pb[1], O[n][1]);
      }
    }
  }

#pragma unroll
  for (int i = 0; i < 2; ++i) {
    float inv = 1.0f / l[i];
    size_t rb = (size_t)(q0 + i * 16 + r16) * 4096 + h * 128 + g * 4;
#pragma unroll
    for (int n = 0; n < 8; ++n) {
      half4v o;
      o[0] = (_Float16)(O[n][i][0] * inv);
      o[1] = (_Float16)(O[n][i][1] * inv);
      o[2] = (_Float16)(O[n][i][2] * inv);
      o[3] = (_Float16)(O[n][i][3] * inv);
      *(half4v*)(yf + rb + n * 16) = o;
    }
  }
}

// ------------------------------------------------------------------
extern "C" void kernel_launch(void* const* d_in, const int* in_sizes, int n_in,
                              void* d_out, int out_size, void* d_ws, size_t ws_size,
                              hipStream_t stream) {
  const float* x = (const float*)d_in[0];
  const float* w_attn = (const float*)d_in[1];
  const float* b_attn = (const float*)d_in[2];
  const float* w_proj = (const float*)d_in[3];
  const float* b_proj = (const float*)d_in[4];
  float* out = (float*)d_out;

  _Float16* xh = (_Float16*)d_ws;
  _Float16* wa = xh + (size_t)2048 * 4096;
  _Float16* wp = wa + (size_t)12288 * 4096;
  _Float16* qfp = wp + (size_t)4096 * 4096;
  _Float16* kfp = qfp + (size_t)32 * 2048 * 128;
  _Float16* vfp = kfp + (size_t)32 * 2048 * 128;
  _Float16* yf = vfp + (size_t)32 * 2048 * 128;
  _Float16* vtp = xh;  // alias: xh dead after qkv GEMM

  cvt_f32_f16<<<(2048 * 4096 / 8 + 255) / 256, 256, 0, stream>>>(x, xh, 2048 * 4096 / 8);
  cvt_f32_f16<<<(12288 * 4096 / 8 + 255) / 256, 256, 0, stream>>>(w_attn, wa, 12288 * 4096 / 8);
  cvt_f32_f16<<<(4096 * 4096 / 8 + 255) / 256, 256, 0, stream>>>(w_proj, wp, 4096 * 4096 / 8);

  // qkv = x @ Wa^T + b (fused RoPE) : M=2048, N=12288 -> grid 48x8 (384 wg, %8==0)
  gemm_nt<<<dim3(48, 8), 512, 0, stream>>>(xh, wa, b_attn, nullptr, 2048, 12288, 4096, 1,
                                           qfp, kfp, vfp);
  transpose_v<<<dim3(2, 32, 32), 256, 0, stream>>>(vfp, vtp);
  attn<<<512, 256, 0, stream>>>(qfp, kfp, vtp, yf);
  // out = y @ Wp^T + b : M=2048, N=4096 -> grid 16x8 (128 wg, %8==0)
  gemm_nt<<<dim3(16, 8), 512, 0, stream>>>(yf, wp, b_proj, out, 2048, 4096, 4096, 0,
                                           nullptr, nullptr, nullptr);
}

// Round 4
// 799.762 us; speedup vs baseline: 1.1366x; 1.1251x over previous
//
#include <hip/hip_runtime.h>

typedef _Float16 half8 __attribute__((ext_vector_type(8)));
typedef _Float16 half4v __attribute__((ext_vector_type(4)));
typedef float floatx4 __attribute__((ext_vector_type(4)));
typedef unsigned int uintx4 __attribute__((ext_vector_type(4)));

#define GLDS16(gsrc, ldst)                                                                  \
  __builtin_amdgcn_global_load_lds((const __attribute__((address_space(1))) void*)(gsrc),   \
                                   (__attribute__((address_space(3))) void*)(ldst), 16, 0, 0)
#define MFMA16(a, b, c) __builtin_amdgcn_mfma_f32_16x16x32_f16(a, b, c, 0, 0, 0)

static __device__ __forceinline__ float fast_exp2(float x) {
#if __has_builtin(__builtin_amdgcn_exp2f)
  return __builtin_amdgcn_exp2f(x);
#else
  return exp2f(x);
#endif
}
static __device__ __forceinline__ int pk2(float a, float b) {
  return __builtin_bit_cast(int, __builtin_amdgcn_cvt_pkrtz(a, b));
}

// ------------------------------------------------------------------
// fp32 -> fp16 convert, 8 elems/thread
// ------------------------------------------------------------------
__global__ __launch_bounds__(256) void cvt_f32_f16(const float* __restrict__ src,
                                                   _Float16* __restrict__ dst, int n8) {
  int i = blockIdx.x * 256 + threadIdx.x;
  if (i >= n8) return;
  const float4* s4 = (const float4*)src;
  float4 a = s4[2 * (size_t)i];
  float4 b = s4[2 * (size_t)i + 1];
  half8 h;
  h[0] = (_Float16)a.x; h[1] = (_Float16)a.y; h[2] = (_Float16)a.z; h[3] = (_Float16)a.w;
  h[4] = (_Float16)b.x; h[5] = (_Float16)b.y; h[6] = (_Float16)b.z; h[7] = (_Float16)b.w;
  *(half8*)(dst + 8 * (size_t)i) = h;
}

// ------------------------------------------------------------------
// NT GEMM: 128x256 tile, BK=32, 4 waves (each 128x64), 2-slot LDS ring (48KB)
// -> 2 blocks/CU. One barrier/tile; stage next tile before compute; vmcnt(0)
// drain at tile end overlaps with the co-resident block's MFMA.
// mode 1: qkv epilogue (bias + RoPE + q prescale). mode 2: split-K partial
// (C + z*M*N, no bias). mode 0: C + bias.
// ------------------------------------------------------------------
__global__ __launch_bounds__(256, 2) void gemm_nt(
    const _Float16* __restrict__ A, const _Float16* __restrict__ W,
    const float* __restrict__ bias, float* __restrict__ C,
    int M, int N, int K, int kdepth, int mode,
    _Float16* __restrict__ qfp, _Float16* __restrict__ kfp, _Float16* __restrict__ vfp) {
  __shared__ __align__(16) _Float16 lds[24576];  // A: 2x4096 halfs, B: 2x8192 halfs
  const int tid = threadIdx.x;
  const int w = tid >> 6, lane = tid & 63;
  const int g = lane >> 4, r16 = lane & 15;
  const int gx = gridDim.x;
  const int nwg = gx * gridDim.y;
  const int flat = blockIdx.y * gx + blockIdx.x;
  const int swz = (flat & 7) * (nwg >> 3) + (flat >> 3);  // nwg % 8 == 0
  const int tn = swz % gx, tm = swz / gx;
  const int m0 = tm * 128, n0 = tn * 256;
  const int z = blockIdx.z;
  const _Float16* Az = A + (size_t)z * kdepth;
  const _Float16* Wz = W + (size_t)z * kdepth;
  const int NT = kdepth >> 5;

  // staging: per wave, A instrs {2w,2w+1} (rows 32w..32w+31), B instrs {4w..4w+3}
  const int l2 = lane >> 2, l3 = lane & 3;
  const int rA0 = 32 * w + l2, rA1 = rA0 + 16;
  const int rB0 = 64 * w + l2, rB1 = rB0 + 16, rB2 = rB0 + 32, rB3 = rB0 + 48;
  const _Float16* pa0 = Az + (size_t)(m0 + rA0) * K + ((l3 ^ ((rA0 >> 1) & 3)) << 3);
  const _Float16* pa1 = Az + (size_t)(m0 + rA1) * K + ((l3 ^ ((rA1 >> 1) & 3)) << 3);
  const _Float16* pw0 = Wz + (size_t)(n0 + rB0) * K + ((l3 ^ ((rB0 >> 1) & 3)) << 3);
  const _Float16* pw1 = Wz + (size_t)(n0 + rB1) * K + ((l3 ^ ((rB1 >> 1) & 3)) << 3);
  const _Float16* pw2 = Wz + (size_t)(n0 + rB2) * K + ((l3 ^ ((rB2 >> 1) & 3)) << 3);
  const _Float16* pw3 = Wz + (size_t)(n0 + rB3) * K + ((l3 ^ ((rB3 >> 1) & 3)) << 3);

#define STAGE(t)                                              \
  {                                                           \
    const int sA_ = ((t) & 1) * 4096;                         \
    const int sB_ = 8192 + ((t) & 1) * 8192;                  \
    const int ko_ = (t) << 5;                                 \
    GLDS16(pa0 + ko_, &lds[sA_ + w * 1024]);                  \
    GLDS16(pa1 + ko_, &lds[sA_ + w * 1024 + 512]);            \
    GLDS16(pw0 + ko_, &lds[sB_ + w * 2048]);                  \
    GLDS16(pw1 + ko_, &lds[sB_ + w * 2048 + 512]);            \
    GLDS16(pw2 + ko_, &lds[sB_ + w * 2048 + 1024]);           \
    GLDS16(pw3 + ko_, &lds[sB_ + w * 2048 + 1536]);           \
  }

  floatx4 acc[8][4] = {};

  STAGE(0);
  asm volatile("s_waitcnt vmcnt(0)" ::: "memory");
  __builtin_amdgcn_s_barrier();
  __builtin_amdgcn_sched_barrier(0);

  const int swzsel = ((r16 >> 1) & 3);
  for (int t = 0; t < NT; ++t) {
    if (t + 1 < NT) STAGE(t + 1);
    const int sA = (t & 1) * 4096, sB = 8192 + (t & 1) * 8192;
    half8 af[8], bf[4];
#pragma unroll
    for (int fm = 0; fm < 8; ++fm)
      af[fm] = *(const half8*)&lds[sA + (fm * 16 + r16) * 32 + ((g ^ swzsel) << 3)];
#pragma unroll
    for (int fn = 0; fn < 4; ++fn)
      bf[fn] = *(const half8*)&lds[sB + (w * 64 + fn * 16 + r16) * 32 + ((g ^ swzsel) << 3)];
    __builtin_amdgcn_s_setprio(1);
#pragma unroll
    for (int fm = 0; fm < 8; ++fm)
#pragma unroll
      for (int fn = 0; fn < 4; ++fn)
        acc[fm][fn] = MFMA16(af[fm], bf[fn], acc[fm][fn]);
    __builtin_amdgcn_s_setprio(0);
    asm volatile("s_waitcnt vmcnt(0)" ::: "memory");
    __builtin_amdgcn_sched_barrier(0);
    __builtin_amdgcn_s_barrier();
    __builtin_amdgcn_sched_barrier(0);
  }
#undef STAGE

  // epilogue: frag layout row=(lane>>4)*4+ri, col=lane&15
  if (mode == 1) {
    const int gc = (n0 + w * 64) >> 7;
    const int h = gc / 3, s = gc - 3 * h;
    _Float16* dst = (s == 0) ? qfp : (s == 1 ? kfp : vfp);
    const float theta = exp2f(-(float)r16 * 0.83048202372184058f);
    const bool dorope = (s < 2) && ((w & 1) == 0);
#pragma unroll
    for (int fm = 0; fm < 8; ++fm)
#pragma unroll
      for (int ri = 0; ri < 4; ++ri) {
        int tt = m0 + fm * 16 + g * 4 + ri;
        float v[4];
#pragma unroll
        for (int j = 0; j < 4; ++j)
          v[j] = acc[fm][j][ri] + bias[n0 + w * 64 + j * 16 + r16];
        if (dorope) {
          float sn, cs;
          sincosf((float)tt * theta, &sn, &cs);
          float a0 = v[0], a1 = v[1];
          v[0] = a0 * cs - a1 * sn;
          v[1] = a1 * cs + a0 * sn;
        }
        if (s == 0) {
#pragma unroll
          for (int j = 0; j < 4; ++j) v[j] *= 0.12751744f;  // 1/sqrt(128)*log2(e)
        }
        size_t rb = ((size_t)h * 2048 + tt) * 128 + (w & 1) * 64 + r16;
#pragma unroll
        for (int j = 0; j < 4; ++j) dst[rb + j * 16] = (_Float16)v[j];
      }
  } else {
    float* Cz = C + (size_t)z * M * N;
#pragma unroll
    for (int fm = 0; fm < 8; ++fm)
#pragma unroll
      for (int ri = 0; ri < 4; ++ri) {
        int row = m0 + fm * 16 + g * 4 + ri;
#pragma unroll
        for (int j = 0; j < 4; ++j) {
          int col = n0 + w * 64 + j * 16 + r16;
          float v = acc[fm][j][ri];
          if (mode == 0) v += bias[col];
          Cz[(size_t)row * N + col] = v;
        }
      }
  }
}

// ------------------------------------------------------------------
// out = p0 + p1 + bias (split-K combine), float4-vectorized
// ------------------------------------------------------------------
__global__ __launch_bounds__(256) void add_bias(const float* __restrict__ p0,
                                                const float* __restrict__ p1,
                                                const float* __restrict__ bias,
                                                float* __restrict__ out) {
  int i = blockIdx.x * 256 + threadIdx.x;  // over 2048*4096/4
  float4 a = ((const float4*)p0)[i];
  float4 b = ((const float4*)p1)[i];
  float4 bi = ((const float4*)bias)[i & 1023];
  float4 o;
  o.x = a.x + b.x + bi.x;
  o.y = a.y + b.y + bi.y;
  o.z = a.z + b.z + bi.z;
  o.w = a.w + b.w + bi.w;
  ((float4*)out)[i] = o;
}

// ------------------------------------------------------------------
// V [H][T][D] f16 -> V^T [H][D][T] f16, 64x64 tiles through LDS.
// ------------------------------------------------------------------
__global__ __launch_bounds__(256) void transpose_v(const _Float16* __restrict__ src,
                                                   _Float16* __restrict__ dst) {
  __shared__ __align__(16) _Float16 tile[64][72];
  const int h = blockIdx.z, tb = blockIdx.y, db = blockIdx.x;
  const int t0 = tb * 64, d0 = db * 64;
  const int r = threadIdx.x >> 2, a = threadIdx.x & 3;
  const _Float16* s = src + ((size_t)h * 2048 + t0 + r) * 128 + d0 + a * 16;
  *(half8*)&tile[r][a * 16] = *(const half8*)s;
  *(half8*)&tile[r][a * 16 + 8] = *(const half8*)(s + 8);
  __syncthreads();
  half8 o0, o1;
#pragma unroll
  for (int e = 0; e < 8; ++e) o0[e] = tile[a * 16 + e][r];
#pragma unroll
  for (int e = 0; e < 8; ++e) o1[e] = tile[a * 16 + 8 + e][r];
  _Float16* dp = dst + ((size_t)h * 128 + d0 + r) * 2048 + t0 + a * 16;
  *(half8*)dp = o0;
  *(half8*)(dp + 8) = o1;
}

// ------------------------------------------------------------------
// Flash attention, causal. 512 blocks (pairing qt/15-qt), 4 waves x 32 q-rows,
// KVBLK=64. K and V^T staged in LDS (2-slot ring, 64KB) via global_load_lds with
// bank-free grp^(row&7) both-sides swizzle, shared by the 4 waves; next tile
// prefetched before compute; one barrier/tile. Swapped QK^T -> lane-local
// softmax; exp2-domain (q pre-scaled); defer-rescale THR=2.
// Uniform trip count nkt=2qt+2: waves 0/1's extra tile is fully masked.
// ------------------------------------------------------------------
__global__ __launch_bounds__(256, 2) void attn(const _Float16* __restrict__ qf,
                                               const _Float16* __restrict__ kf,
                                               const _Float16* __restrict__ vt,
                                               _Float16* __restrict__ yf) {
  __shared__ __align__(16) _Float16 SL[32768];  // K: 2x8192 halfs, V: 2x8192 at +16384
  const int bid = blockIdx.x;
  const int halfsel = bid >> 8, idx = bid & 255;
  const int h = idx & 31, qb = idx >> 5;
  const int qt = halfsel ? qb : 15 - qb;
  const int lane = threadIdx.x & 63, wave = threadIdx.x >> 6;
  const int g = lane >> 4, r16 = lane & 15;
  const int q0 = qt * 128 + wave * 32;
  const _Float16* qh = qf + (size_t)h * (2048 * 128);
  const _Float16* kh = kf + (size_t)h * (2048 * 128);
  const _Float16* vh = vt + (size_t)h * (128 * 2048);

  half8 qfr[2][4];
#pragma unroll
  for (int i = 0; i < 2; ++i)
#pragma unroll
    for (int kk = 0; kk < 4; ++kk)
      qfr[i][kk] = *(const half8*)(qh + (size_t)(q0 + i * 16 + r16) * 128 + kk * 32 + g * 8);

  floatx4 O[8][2] = {};
  float m[2] = {-1e30f, -1e30f}, l[2] = {0.f, 0.f};
  const int nkt = 2 * qt + 2;

  const int l4 = lane >> 4, l15 = lane & 15, l3v = lane >> 3, l7 = lane & 7;

#define ASTAGE(kt_)                                                                          \
  {                                                                                          \
    const int sl_ = (kt_) & 1;                                                               \
    const int k0_ = (kt_) * 64;                                                              \
    _Float16* kb_ = &SL[sl_ * 8192 + wave * 2048];                                           \
    _Float16* vb_ = &SL[16384 + sl_ * 8192 + wave * 2048];                                   \
    _Pragma("unroll") for (int j_ = 0; j_ < 4; ++j_) {                                       \
      const int krow_ = 16 * wave + 4 * j_ + l4;                                             \
      GLDS16(kh + (size_t)(k0_ + krow_) * 128 + ((l15 ^ (krow_ & 7)) << 3), kb_ + j_ * 512); \
      const int vrow_ = 32 * wave + 8 * j_ + l3v;                                            \
      GLDS16(vh + (size_t)vrow_ * 2048 + k0_ + ((l7 ^ l3v) << 3), vb_ + j_ * 512);           \
    }                                                                                        \
  }

  ASTAGE(0);
  asm volatile("s_waitcnt vmcnt(0)" ::: "memory");
  __builtin_amdgcn_s_barrier();
  __builtin_amdgcn_sched_barrier(0);

  const int kswz = r16 & 7;
  for (int kt = 0; kt < nkt; ++kt) {
    const int slot = kt & 1;
    const int k0 = kt * 64;
    if (kt + 1 < nkt) ASTAGE(kt + 1);

    // --- S^T = K @ Q from LDS K tile ---
    floatx4 S[4][2] = {};
    const int kbase = slot * 8192;
#pragma unroll
    for (int j = 0; j < 4; ++j) {
      const int rb = kbase + (j * 16 + r16) * 128;
      half8 kf0 = *(const half8*)&SL[rb + (((0 + g) ^ kswz) << 3)];
      half8 kf1 = *(const half8*)&SL[rb + (((4 + g) ^ kswz) << 3)];
      half8 kf2 = *(const half8*)&SL[rb + (((8 + g) ^ kswz) << 3)];
      half8 kf3 = *(const half8*)&SL[rb + (((12 + g) ^ kswz) << 3)];
      S[j][0] = MFMA16(kf0, qfr[0][0], S[j][0]);
      S[j][1] = MFMA16(kf0, qfr[1][0], S[j][1]);
      S[j][0] = MFMA16(kf1, qfr[0][1], S[j][0]);
      S[j][1] = MFMA16(kf1, qfr[1][1], S[j][1]);
      S[j][0] = MFMA16(kf2, qfr[0][2], S[j][0]);
      S[j][1] = MFMA16(kf2, qfr[1][2], S[j][1]);
      S[j][0] = MFMA16(kf3, qfr[0][3], S[j][0]);
      S[j][1] = MFMA16(kf3, qfr[1][3], S[j][1]);
    }

    // --- causal mask (uniform guard; waves 0/1's final tile is fully masked) ---
    if (kt >= 2 * qt) {
#pragma unroll
      for (int j = 0; j < 4; ++j)
#pragma unroll
        for (int r = 0; r < 4; ++r) {
          int key = k0 + j * 16 + g * 4 + r;
#pragma unroll
          for (int i = 0; i < 2; ++i)
            if (key > q0 + i * 16 + r16) S[j][i][r] = -1e30f;
        }
    }

    // --- row max (in-lane 16 + xor 16/32) ---
    float rm[2];
#pragma unroll
    for (int i = 0; i < 2; ++i) {
      float a0 = fmaxf(fmaxf(S[0][i][0], S[0][i][1]), fmaxf(S[0][i][2], S[0][i][3]));
      float a1 = fmaxf(fmaxf(S[1][i][0], S[1][i][1]), fmaxf(S[1][i][2], S[1][i][3]));
      float a2 = fmaxf(fmaxf(S[2][i][0], S[2][i][1]), fmaxf(S[2][i][2], S[2][i][3]));
      float a3 = fmaxf(fmaxf(S[3][i][0], S[3][i][1]), fmaxf(S[3][i][2], S[3][i][3]));
      float a = fmaxf(fmaxf(a0, a1), fmaxf(a2, a3));
      a = fmaxf(a, __shfl_xor(a, 16));
      a = fmaxf(a, __shfl_xor(a, 32));
      rm[i] = a;
    }

    // --- deferred rescale (THR=2 in log2 domain) ---
    if (__any((rm[0] > m[0] + 2.0f) || (rm[1] > m[1] + 2.0f))) {
#pragma unroll
      for (int i = 0; i < 2; ++i) {
        float mn = fmaxf(m[i], rm[i]);
        float corr = fast_exp2(m[i] - mn);
        m[i] = mn;
        l[i] *= corr;
#pragma unroll
        for (int n = 0; n < 8; ++n) O[n][i] = O[n][i] * corr;
      }
    }

    // --- p = exp2(S - m); row sum ---
#pragma unroll
    for (int i = 0; i < 2; ++i) {
      float s = 0.f;
#pragma unroll
      for (int j = 0; j < 4; ++j)
#pragma unroll
        for (int r = 0; r < 4; ++r) {
          float p = fast_exp2(S[j][i][r] - m[i]);
          S[j][i][r] = p;
          s += p;
        }
      s += __shfl_xor(s, 16);
      s += __shfl_xor(s, 32);
      l[i] += s;
    }

    // --- O^T += V^T @ P^T from LDS V tile ---
    const int vbase = 16384 + slot * 8192;
#pragma unroll
    for (int c = 0; c < 2; ++c) {
      half8 pb[2];
#pragma unroll
      for (int i = 0; i < 2; ++i) {
        int s0 = pk2(S[2 * c][i][0], S[2 * c][i][1]);
        int s1 = pk2(S[2 * c][i][2], S[2 * c][i][3]);
        int s2 = pk2(S[2 * c + 1][i][0], S[2 * c + 1][i][1]);
        int s3 = pk2(S[2 * c + 1][i][2], S[2 * c + 1][i][3]);
        int la = ((g & 1) << 5) + r16;
        int lb = la + 16;
        int t0a = __shfl(s0, la), t2a = __shfl(s2, la);
        int t1a = __shfl(s1, la), t3a = __shfl(s3, la);
        int t0b = __shfl(s0, lb), t2b = __shfl(s2, lb);
        int t1b = __shfl(s1, lb), t3b = __shfl(s3, lb);
        uintx4 wv;
        wv[0] = (g < 2) ? (unsigned)t0a : (unsigned)t2a;
        wv[1] = (g < 2) ? (unsigned)t1a : (unsigned)t3a;
        wv[2] = (g < 2) ? (unsigned)t0b : (unsigned)t2b;
        wv[3] = (g < 2) ? (unsigned)t1b : (unsigned)t3b;
        pb[i] = __builtin_bit_cast(half8, wv);
      }
#pragma unroll
      for (int n = 0; n < 8; ++n) {
        half8 va = *(const half8*)&SL[vbase + (n * 16 + r16) * 64 + ((((c << 2) + g) ^ kswz) << 3)];
        O[n][0] = MFMA16(va, pb[0], O[n][0]);
        O[n][1] = MFMA16(va, pb[1], O[n][1]);
      }
    }

    asm volatile("s_waitcnt vmcnt(0)" ::: "memory");
    __builtin_amdgcn_sched_barrier(0);
    __builtin_amdgcn_s_barrier();
    __builtin_amdgcn_sched_barrier(0);
  }
#undef ASTAGE

  // --- epilogue: y[t][h*128+d] f16, d = n*16+g*4+ri ---
#pragma unroll
  for (int i = 0; i < 2; ++i) {
    float inv = 1.0f / l[i];
    size_t rb = (size_t)(q0 + i * 16 + r16) * 4096 + h * 128 + g * 4;
#pragma unroll
    for (int n = 0; n < 8; ++n) {
      half4v o;
      o[0] = (_Float16)(O[n][i][0] * inv);
      o[1] = (_Float16)(O[n][i][1] * inv);
      o[2] = (_Float16)(O[n][i][2] * inv);
      o[3] = (_Float16)(O[n][i][3] * inv);
      *(half4v*)(yf + rb + n * 16) = o;
    }
  }
}

// ------------------------------------------------------------------
extern "C" void kernel_launch(void* const* d_in, const int* in_sizes, int n_in,
                              void* d_out, int out_size, void* d_ws, size_t ws_size,
                              hipStream_t stream) {
  const float* x = (const float*)d_in[0];
  const float* w_attn = (const float*)d_in[1];
  const float* b_attn = (const float*)d_in[2];
  const float* w_proj = (const float*)d_in[3];
  const float* b_proj = (const float*)d_in[4];
  float* out = (float*)d_out;

  _Float16* xh = (_Float16*)d_ws;
  _Float16* wa = xh + (size_t)2048 * 4096;
  _Float16* wp = wa + (size_t)12288 * 4096;
  _Float16* qfp = wp + (size_t)4096 * 4096;
  _Float16* kfp = qfp + (size_t)32 * 2048 * 128;
  _Float16* vfp = kfp + (size_t)32 * 2048 * 128;
  _Float16* yf = vfp + (size_t)32 * 2048 * 128;
  _Float16* vtp = xh;            // alias: xh dead after qkv GEMM
  float* pK = (float*)wa;        // alias: wa dead after qkv GEMM; 2x 33.5MB partials

  cvt_f32_f16<<<(2048 * 4096 / 8 + 255) / 256, 256, 0, stream>>>(x, xh, 2048 * 4096 / 8);
  cvt_f32_f16<<<(12288 * 4096 / 8 + 255) / 256, 256, 0, stream>>>(w_attn, wa, 12288 * 4096 / 8);
  cvt_f32_f16<<<(4096 * 4096 / 8 + 255) / 256, 256, 0, stream>>>(w_proj, wp, 4096 * 4096 / 8);

  // qkv = x @ Wa^T + b (fused RoPE): grid 48x16 = 768 blocks, 2/CU
  gemm_nt<<<dim3(48, 16, 1), 256, 0, stream>>>(xh, wa, b_attn, nullptr, 2048, 12288, 4096,
                                               4096, 1, qfp, kfp, vfp);
  transpose_v<<<dim3(2, 32, 32), 256, 0, stream>>>(vfp, vtp);
  attn<<<512, 256, 0, stream>>>(qfp, kfp, vtp, yf);
  // proj split-K2: one dispatch, 16x16x2 = 512 half-K blocks -> full chip
  gemm_nt<<<dim3(16, 16, 2), 256, 0, stream>>>(yf, wp, nullptr, pK, 2048, 4096, 4096,
                                               2048, 2, nullptr, nullptr, nullptr);
  add_bias<<<2048 * 4096 / 4 / 256, 256, 0, stream>>>(pK, pK + (size_t)2048 * 4096, b_proj, out);
}

// Round 5
// 778.370 us; speedup vs baseline: 1.1678x; 1.0275x over previous
//
#include <hip/hip_runtime.h>

typedef _Float16 half8 __attribute__((ext_vector_type(8)));
typedef _Float16 half4v __attribute__((ext_vector_type(4)));
typedef float floatx4 __attribute__((ext_vector_type(4)));
typedef unsigned int uintx4 __attribute__((ext_vector_type(4)));

#define GLDS16(gsrc, ldst)                                                                  \
  __builtin_amdgcn_global_load_lds((const __attribute__((address_space(1))) void*)(gsrc),   \
                                   (__attribute__((address_space(3))) void*)(ldst), 16, 0, 0)
#define MFMA16(a, b, c) __builtin_amdgcn_mfma_f32_16x16x32_f16(a, b, c, 0, 0, 0)

static __device__ __forceinline__ float fast_exp2(float x) {
#if __has_builtin(__builtin_amdgcn_exp2f)
  return __builtin_amdgcn_exp2f(x);
#else
  return exp2f(x);
#endif
}
static __device__ __forceinline__ int pk2(float a, float b) {
  return __builtin_bit_cast(int, __builtin_amdgcn_cvt_pkrtz(a, b));
}

// ------------------------------------------------------------------
// fp32 -> fp16 convert, 8 elems/thread
// ------------------------------------------------------------------
__global__ __launch_bounds__(256) void cvt_f32_f16(const float* __restrict__ src,
                                                   _Float16* __restrict__ dst, int n8) {
  int i = blockIdx.x * 256 + threadIdx.x;
  if (i >= n8) return;
  const float4* s4 = (const float4*)src;
  float4 a = s4[2 * (size_t)i];
  float4 b = s4[2 * (size_t)i + 1];
  half8 h;
  h[0] = (_Float16)a.x; h[1] = (_Float16)a.y; h[2] = (_Float16)a.z; h[3] = (_Float16)a.w;
  h[4] = (_Float16)b.x; h[5] = (_Float16)b.y; h[6] = (_Float16)b.z; h[7] = (_Float16)b.w;
  *(half8*)(dst + 8 * (size_t)i) = h;
}

// ------------------------------------------------------------------
// NT GEMM: 128x256 tile, BK=32, 8 waves (2Mx4N, per-wave 64x64 = acc[4][4]).
// 6-slot LDS K-tile ring (144KB): during tile t stage tile t+4 (slot (t+4)%6,
// last read at t-2 -> race-free). End-of-tile counted vmcnt(9): 3 tiles x 3
// loads stay in flight; exact tail ladder 9/6/3/0. Per tile-phase: 8 ds_read
// + 3 global_load_lds + 16 MFMA between 2 raw barriers, setprio around MFMA.
// Block order: tm fast / tn slow (B-panels L3-resident, A streams once).
// mode 1: qkv epilogue (bias+RoPE+q prescale). mode 2: split-K partial.
// ------------------------------------------------------------------
__global__ __launch_bounds__(512) void gemm_nt(
    const _Float16* __restrict__ A, const _Float16* __restrict__ W,
    const float* __restrict__ bias, float* __restrict__ C,
    int M, int N, int K, int kdepth, int mode,
    _Float16* __restrict__ qfp, _Float16* __restrict__ kfp, _Float16* __restrict__ vfp) {
  // per slot: A 128x32 (4096 halfs) + B 256x32 (8192 halfs) = 12288 halfs; 6 slots
  __shared__ __align__(16) _Float16 lds[73728];
  const int tid = threadIdx.x;
  const int w = tid >> 6, lane = tid & 63;
  const int wm = w >> 2, wn = w & 3;
  const int g = lane >> 4, r16 = lane & 15;
  const int gx = gridDim.x;  // N tiles
  const int gy = gridDim.y;  // M tiles
  const int nwg = gx * gy;
  const int flat = blockIdx.y * gx + blockIdx.x;
  const int c = (flat & 7) * (nwg >> 3) + (flat >> 3);  // XCD-chunked id (nwg%8==0)
  const int tm = c % gy, tn = c / gy;                   // tm FAST: B-panel locality
  const int m0 = tm * 128, n0 = tn * 256;
  const int z = blockIdx.z;
  const _Float16* Az = A + (size_t)z * kdepth;
  const _Float16* Wz = W + (size_t)z * kdepth;
  const int NT = kdepth >> 5;

  // staging geometry: 4 threads/row (row = 32 halfs = 4x16B), src col pre-swizzled
  const int sr = tid >> 2, sc = tid & 3;
  const int scA = ((sc ^ ((sr >> 1) & 3)) << 3);
  const int srB1 = 128 + sr;
  const int scB1 = ((sc ^ ((srB1 >> 1) & 3)) << 3);
  const _Float16* pa = Az + (size_t)(m0 + sr) * K + scA;       // A rows 0..127
  const _Float16* pb0 = Wz + (size_t)(n0 + sr) * K + scA;      // B rows 0..127
  const _Float16* pb1 = Wz + (size_t)(n0 + srB1) * K + scB1;   // B rows 128..255
  const int wbase = w * 512;  // per-wave LDS dest chunk (64 lanes x 8 halfs)

#define STAGE(t_, slot_)                                   \
  {                                                        \
    const int ko_ = (t_) << 5;                             \
    const int sb_ = (slot_)*12288;                         \
    GLDS16(pa + ko_, &lds[sb_ + wbase]);                   \
    GLDS16(pb0 + ko_, &lds[sb_ + 4096 + wbase]);           \
    GLDS16(pb1 + ko_, &lds[sb_ + 8192 + wbase]);           \
  }

  floatx4 acc[4][4] = {};

  // prologue: stage tiles 0..3 (12 loads); tile0 ready when <=9 remain
  STAGE(0, 0);
  STAGE(1, 1);
  STAGE(2, 2);
  STAGE(3, 3);
  asm volatile("s_waitcnt vmcnt(9)" ::: "memory");
  __builtin_amdgcn_s_barrier();
  __builtin_amdgcn_sched_barrier(0);

  const int swzsel = (r16 >> 1) & 3;
  int sC = 0, sS = 4;  // ring slots for tile t and t+4
  for (int t = 0; t < NT; ++t) {
    if (t + 4 < NT) STAGE(t + 4, sS);
    const int ab = sC * 12288, bb = ab + 4096;
    half8 af[4], bf[4];
#pragma unroll
    for (int fm = 0; fm < 4; ++fm) {
      int arow = wm * 64 + fm * 16 + r16;
      af[fm] = *(const half8*)&lds[ab + arow * 32 + ((g ^ swzsel) << 3)];
    }
#pragma unroll
    for (int fn = 0; fn < 4; ++fn) {
      int brow = wn * 64 + fn * 16 + r16;
      bf[fn] = *(const half8*)&lds[bb + brow * 32 + ((g ^ swzsel) << 3)];
    }
    __builtin_amdgcn_s_barrier();
    __builtin_amdgcn_sched_barrier(0);
    __builtin_amdgcn_s_setprio(1);
#pragma unroll
    for (int fm = 0; fm < 4; ++fm)
#pragma unroll
      for (int fn = 0; fn < 4; ++fn)
        acc[fm][fn] = MFMA16(af[fm], bf[fn], acc[fm][fn]);
    __builtin_amdgcn_s_setprio(0);
    // counted end-of-tile wait: ensure tile t+1's 3 loads retired.
    // younger-in-flight = 3 * min(3, r-1), r = NT-1-t
    {
      const int r = NT - 1 - t;
      if (r >= 4)
        asm volatile("s_waitcnt vmcnt(9)" ::: "memory");
      else if (r == 3)
        asm volatile("s_waitcnt vmcnt(6)" ::: "memory");
      else if (r == 2)
        asm volatile("s_waitcnt vmcnt(3)" ::: "memory");
      else if (r == 1)
        asm volatile("s_waitcnt vmcnt(0)" ::: "memory");
    }
    __builtin_amdgcn_sched_barrier(0);
    __builtin_amdgcn_s_barrier();
    if (++sC == 6) sC = 0;
    if (++sS == 6) sS = 0;
  }
#undef STAGE

  // epilogue: frag layout row=(lane>>4)*4+ri, col=lane&15
  if (mode == 1) {
    const int gc = (n0 + wn * 64) >> 7;
    const int h = gc / 3, s = gc - 3 * h;
    _Float16* dst = (s == 0) ? qfp : (s == 1 ? kfp : vfp);
    const float theta = exp2f(-(float)r16 * 0.83048202372184058f);
    const bool dorope = (s < 2) && ((wn & 1) == 0);
#pragma unroll
    for (int fm = 0; fm < 4; ++fm)
#pragma unroll
      for (int ri = 0; ri < 4; ++ri) {
        int tt = m0 + wm * 64 + fm * 16 + g * 4 + ri;
        float v[4];
#pragma unroll
        for (int j = 0; j < 4; ++j)
          v[j] = acc[fm][j][ri] + bias[n0 + wn * 64 + j * 16 + r16];
        if (dorope) {
          float sn, cs;
          sincosf((float)tt * theta, &sn, &cs);
          float a0 = v[0], a1 = v[1];
          v[0] = a0 * cs - a1 * sn;
          v[1] = a1 * cs + a0 * sn;
        }
        if (s == 0) {
#pragma unroll
          for (int j = 0; j < 4; ++j) v[j] *= 0.12751744f;  // 1/sqrt(128)*log2(e)
        }
        size_t rb = ((size_t)h * 2048 + tt) * 128 + (wn & 1) * 64 + r16;
#pragma unroll
        for (int j = 0; j < 4; ++j) dst[rb + j * 16] = (_Float16)v[j];
      }
  } else {
    float* Cz = C + (size_t)z * M * N;
#pragma unroll
    for (int fm = 0; fm < 4; ++fm)
#pragma unroll
      for (int ri = 0; ri < 4; ++ri) {
        int row = m0 + wm * 64 + fm * 16 + g * 4 + ri;
#pragma unroll
        for (int j = 0; j < 4; ++j) {
          int col = n0 + wn * 64 + j * 16 + r16;
          float v = acc[fm][j][ri];
          if (mode == 0) v += bias[col];
          Cz[(size_t)row * N + col] = v;
        }
      }
  }
}

// ------------------------------------------------------------------
// out = p0 + p1 + bias (split-K combine), float4-vectorized
// ------------------------------------------------------------------
__global__ __launch_bounds__(256) void add_bias(const float* __restrict__ p0,
                                                const float* __restrict__ p1,
                                                const float* __restrict__ bias,
                                                float* __restrict__ out) {
  int i = blockIdx.x * 256 + threadIdx.x;  // over 2048*4096/4
  float4 a = ((const float4*)p0)[i];
  float4 b = ((const float4*)p1)[i];
  float4 bi = ((const float4*)bias)[i & 1023];
  float4 o;
  o.x = a.x + b.x + bi.x;
  o.y = a.y + b.y + bi.y;
  o.z = a.z + b.z + bi.z;
  o.w = a.w + b.w + bi.w;
  ((float4*)out)[i] = o;
}

// ------------------------------------------------------------------
// V [H][T][D] f16 -> V^T [H][D][T] f16, 64x64 tiles through LDS.
// ------------------------------------------------------------------
__global__ __launch_bounds__(256) void transpose_v(const _Float16* __restrict__ src,
                                                   _Float16* __restrict__ dst) {
  __shared__ __align__(16) _Float16 tile[64][72];
  const int h = blockIdx.z, tb = blockIdx.y, db = blockIdx.x;
  const int t0 = tb * 64, d0 = db * 64;
  const int r = threadIdx.x >> 2, a = threadIdx.x & 3;
  const _Float16* s = src + ((size_t)h * 2048 + t0 + r) * 128 + d0 + a * 16;
  *(half8*)&tile[r][a * 16] = *(const half8*)s;
  *(half8*)&tile[r][a * 16 + 8] = *(const half8*)(s + 8);
  __syncthreads();
  half8 o0, o1;
#pragma unroll
  for (int e = 0; e < 8; ++e) o0[e] = tile[a * 16 + e][r];
#pragma unroll
  for (int e = 0; e < 8; ++e) o1[e] = tile[a * 16 + 8 + e][r];
  _Float16* dp = dst + ((size_t)h * 128 + d0 + r) * 2048 + t0 + a * 16;
  *(half8*)dp = o0;
  *(half8*)(dp + 8) = o1;
}

// ------------------------------------------------------------------
// Flash attention (byte-identical to R4)
// ------------------------------------------------------------------
__global__ __launch_bounds__(256, 2) void attn(const _Float16* __restrict__ qf,
                                               const _Float16* __restrict__ kf,
                                               const _Float16* __restrict__ vt,
                                               _Float16* __restrict__ yf) {
  __shared__ __align__(16) _Float16 SL[32768];  // K: 2x8192 halfs, V: 2x8192 at +16384
  const int bid = blockIdx.x;
  const int halfsel = bid >> 8, idx = bid & 255;
  const int h = idx & 31, qb = idx >> 5;
  const int qt = halfsel ? qb : 15 - qb;
  const int lane = threadIdx.x & 63, wave = threadIdx.x >> 6;
  const int g = lane >> 4, r16 = lane & 15;
  const int q0 = qt * 128 + wave * 32;
  const _Float16* qh = qf + (size_t)h * (2048 * 128);
  const _Float16* kh = kf + (size_t)h * (2048 * 128);
  const _Float16* vh = vt + (size_t)h * (128 * 2048);

  half8 qfr[2][4];
#pragma unroll
  for (int i = 0; i < 2; ++i)
#pragma unroll
    for (int kk = 0; kk < 4; ++kk)
      qfr[i][kk] = *(const half8*)(qh + (size_t)(q0 + i * 16 + r16) * 128 + kk * 32 + g * 8);

  floatx4 O[8][2] = {};
  float m[2] = {-1e30f, -1e30f}, l[2] = {0.f, 0.f};
  const int nkt = 2 * qt + 2;

  const int l4 = lane >> 4, l15 = lane & 15, l3v = lane >> 3, l7 = lane & 7;

#define ASTAGE(kt_)                                                                          \
  {                                                                                          \
    const int sl_ = (kt_) & 1;                                                               \
    const int k0_ = (kt_) * 64;                                                              \
    _Float16* kb_ = &SL[sl_ * 8192 + wave * 2048];                                           \
    _Float16* vb_ = &SL[16384 + sl_ * 8192 + wave * 2048];                                   \
    _Pragma("unroll") for (int j_ = 0; j_ < 4; ++j_) {                                       \
      const int krow_ = 16 * wave + 4 * j_ + l4;                                             \
      GLDS16(kh + (size_t)(k0_ + krow_) * 128 + ((l15 ^ (krow_ & 7)) << 3), kb_ + j_ * 512); \
      const int vrow_ = 32 * wave + 8 * j_ + l3v;                                            \
      GLDS16(vh + (size_t)vrow_ * 2048 + k0_ + ((l7 ^ l3v) << 3), vb_ + j_ * 512);           \
    }                                                                                        \
  }

  ASTAGE(0);
  asm volatile("s_waitcnt vmcnt(0)" ::: "memory");
  __builtin_amdgcn_s_barrier();
  __builtin_amdgcn_sched_barrier(0);

  const int kswz = r16 & 7;
  for (int kt = 0; kt < nkt; ++kt) {
    const int slot = kt & 1;
    const int k0 = kt * 64;
    if (kt + 1 < nkt) ASTAGE(kt + 1);

    floatx4 S[4][2] = {};
    const int kbase = slot * 8192;
#pragma unroll
    for (int j = 0; j < 4; ++j) {
      const int rb = kbase + (j * 16 + r16) * 128;
      half8 kf0 = *(const half8*)&SL[rb + (((0 + g) ^ kswz) << 3)];
      half8 kf1 = *(const half8*)&SL[rb + (((4 + g) ^ kswz) << 3)];
      half8 kf2 = *(const half8*)&SL[rb + (((8 + g) ^ kswz) << 3)];
      half8 kf3 = *(const half8*)&SL[rb + (((12 + g) ^ kswz) << 3)];
      S[j][0] = MFMA16(kf0, qfr[0][0], S[j][0]);
      S[j][1] = MFMA16(kf0, qfr[1][0], S[j][1]);
      S[j][0] = MFMA16(kf1, qfr[0][1], S[j][0]);
      S[j][1] = MFMA16(kf1, qfr[1][1], S[j][1]);
      S[j][0] = MFMA16(kf2, qfr[0][2], S[j][0]);
      S[j][1] = MFMA16(kf2, qfr[1][2], S[j][1]);
      S[j][0] = MFMA16(kf3, qfr[0][3], S[j][0]);
      S[j][1] = MFMA16(kf3, qfr[1][3], S[j][1]);
    }

    if (kt >= 2 * qt) {
#pragma unroll
      for (int j = 0; j < 4; ++j)
#pragma unroll
        for (int r = 0; r < 4; ++r) {
          int key = k0 + j * 16 + g * 4 + r;
#pragma unroll
          for (int i = 0; i < 2; ++i)
            if (key > q0 + i * 16 + r16) S[j][i][r] = -1e30f;
        }
    }

    float rm[2];
#pragma unroll
    for (int i = 0; i < 2; ++i) {
      float a0 = fmaxf(fmaxf(S[0][i][0], S[0][i][1]), fmaxf(S[0][i][2], S[0][i][3]));
      float a1 = fmaxf(fmaxf(S[1][i][0], S[1][i][1]), fmaxf(S[1][i][2], S[1][i][3]));
      float a2 = fmaxf(fmaxf(S[2][i][0], S[2][i][1]), fmaxf(S[2][i][2], S[2][i][3]));
      float a3 = fmaxf(fmaxf(S[3][i][0], S[3][i][1]), fmaxf(S[3][i][2], S[3][i][3]));
      float a = fmaxf(fmaxf(a0, a1), fmaxf(a2, a3));
      a = fmaxf(a, __shfl_xor(a, 16));
      a = fmaxf(a, __shfl_xor(a, 32));
      rm[i] = a;
    }

    if (__any((rm[0] > m[0] + 2.0f) || (rm[1] > m[1] + 2.0f))) {
#pragma unroll
      for (int i = 0; i < 2; ++i) {
        float mn = fmaxf(m[i], rm[i]);
        float corr = fast_exp2(m[i] - mn);
        m[i] = mn;
        l[i] *= corr;
#pragma unroll
        for (int n = 0; n < 8; ++n) O[n][i] = O[n][i] * corr;
      }
    }

#pragma unroll
    for (int i = 0; i < 2; ++i) {
      float s = 0.f;
#pragma unroll
      for (int j = 0; j < 4; ++j)
#pragma unroll
        for (int r = 0; r < 4; ++r) {
          float p = fast_exp2(S[j][i][r] - m[i]);
          S[j][i][r] = p;
          s += p;
        }
      s += __shfl_xor(s, 16);
      s += __shfl_xor(s, 32);
      l[i] += s;
    }

    const int vbase = 16384 + slot * 8192;
#pragma unroll
    for (int cc = 0; cc < 2; ++cc) {
      half8 pb[2];
#pragma unroll
      for (int i = 0; i < 2; ++i) {
        int s0 = pk2(S[2 * cc][i][0], S[2 * cc][i][1]);
        int s1 = pk2(S[2 * cc][i][2], S[2 * cc][i][3]);
        int s2 = pk2(S[2 * cc + 1][i][0], S[2 * cc + 1][i][1]);
        int s3 = pk2(S[2 * cc + 1][i][2], S[2 * cc + 1][i][3]);
        int la = ((g & 1) << 5) + r16;
        int lb = la + 16;
        int t0a = __shfl(s0, la), t2a = __shfl(s2, la);
        int t1a = __shfl(s1, la), t3a = __shfl(s3, la);
        int t0b = __shfl(s0, lb), t2b = __shfl(s2, lb);
        int t1b = __shfl(s1, lb), t3b = __shfl(s3, lb);
        uintx4 wv;
        wv[0] = (g < 2) ? (unsigned)t0a : (unsigned)t2a;
        wv[1] = (g < 2) ? (unsigned)t1a : (unsigned)t3a;
        wv[2] = (g < 2) ? (unsigned)t0b : (unsigned)t2b;
        wv[3] = (g < 2) ? (unsigned)t1b : (unsigned)t3b;
        pb[i] = __builtin_bit_cast(half8, wv);
      }
#pragma unroll
      for (int n = 0; n < 8; ++n) {
        half8 va = *(const half8*)&SL[vbase + (n * 16 + r16) * 64 + ((((cc << 2) + g) ^ kswz) << 3)];
        O[n][0] = MFMA16(va, pb[0], O[n][0]);
        O[n][1] = MFMA16(va, pb[1], O[n][1]);
      }
    }

    asm volatile("s_waitcnt vmcnt(0)" ::: "memory");
    __builtin_amdgcn_sched_barrier(0);
    __builtin_amdgcn_s_barrier();
    __builtin_amdgcn_sched_barrier(0);
  }
#undef ASTAGE

#pragma unroll
  for (int i = 0; i < 2; ++i) {
    float inv = 1.0f / l[i];
    size_t rb = (size_t)(q0 + i * 16 + r16) * 4096 + h * 128 + g * 4;
#pragma unroll
    for (int n = 0; n < 8; ++n) {
      half4v o;
      o[0] = (_Float16)(O[n][i][0] * inv);
      o[1] = (_Float16)(O[n][i][1] * inv);
      o[2] = (_Float16)(O[n][i][2] * inv);
      o[3] = (_Float16)(O[n][i][3] * inv);
      *(half4v*)(yf + rb + n * 16) = o;
    }
  }
}

// ------------------------------------------------------------------
extern "C" void kernel_launch(void* const* d_in, const int* in_sizes, int n_in,
                              void* d_out, int out_size, void* d_ws, size_t ws_size,
                              hipStream_t stream) {
  const float* x = (const float*)d_in[0];
  const float* w_attn = (const float*)d_in[1];
  const float* b_attn = (const float*)d_in[2];
  const float* w_proj = (const float*)d_in[3];
  const float* b_proj = (const float*)d_in[4];
  float* out = (float*)d_out;

  _Float16* xh = (_Float16*)d_ws;
  _Float16* wa = xh + (size_t)2048 * 4096;
  _Float16* wp = wa + (size_t)12288 * 4096;
  _Float16* qfp = wp + (size_t)4096 * 4096;
  _Float16* kfp = qfp + (size_t)32 * 2048 * 128;
  _Float16* vfp = kfp + (size_t)32 * 2048 * 128;
  _Float16* yf = vfp + (size_t)32 * 2048 * 128;
  _Float16* vtp = xh;            // alias: xh dead after qkv GEMM
  float* pK = (float*)wa;        // alias: wa dead after qkv GEMM; 2x 33.5MB partials

  cvt_f32_f16<<<(2048 * 4096 / 8 + 255) / 256, 256, 0, stream>>>(x, xh, 2048 * 4096 / 8);
  cvt_f32_f16<<<(12288 * 4096 / 8 + 255) / 256, 256, 0, stream>>>(w_attn, wa, 12288 * 4096 / 8);
  cvt_f32_f16<<<(4096 * 4096 / 8 + 255) / 256, 256, 0, stream>>>(w_proj, wp, 4096 * 4096 / 8);

  // qkv = x @ Wa^T + b (fused RoPE): grid 48(N) x 16(M) = 768 blocks, 3/CU
  gemm_nt<<<dim3(48, 16, 1), 512, 0, stream>>>(xh, wa, b_attn, nullptr, 2048, 12288, 4096,
                                               4096, 1, qfp, kfp, vfp);
  transpose_v<<<dim3(2, 32, 32), 256, 0, stream>>>(vfp, vtp);
  attn<<<512, 256, 0, stream>>>(qfp, kfp, vtp, yf);
  // proj split-K2: grid 16(N) x 16(M) x 2 = 512 blocks, 2/CU
  gemm_nt<<<dim3(16, 16, 2), 512, 0, stream>>>(yf, wp, nullptr, pK, 2048, 4096, 4096,
                                               2048, 2, nullptr, nullptr, nullptr);
  add_bias<<<2048 * 4096 / 4 / 256, 256, 0, stream>>>(pK, pK + (size_t)2048 * 4096, b_proj, out);
}

// Round 6
// 765.569 us; speedup vs baseline: 1.1873x; 1.0167x over previous
//
#include <hip/hip_runtime.h>

typedef _Float16 half8 __attribute__((ext_vector_type(8)));
typedef _Float16 half4v __attribute__((ext_vector_type(4)));
typedef float floatx4 __attribute__((ext_vector_type(4)));
typedef unsigned int uintx4 __attribute__((ext_vector_type(4)));

#define GLDS16(gsrc, ldst)                                                                  \
  __builtin_amdgcn_global_load_lds((const __attribute__((address_space(1))) void*)(gsrc),   \
                                   (__attribute__((address_space(3))) void*)(ldst), 16, 0, 0)
#define MFMA16(a, b, c) __builtin_amdgcn_mfma_f32_16x16x32_f16(a, b, c, 0, 0, 0)

static __device__ __forceinline__ float fast_exp2(float x) {
#if __has_builtin(__builtin_amdgcn_exp2f)
  return __builtin_amdgcn_exp2f(x);
#else
  return exp2f(x);
#endif
}
static __device__ __forceinline__ int pk2(float a, float b) {
  return __builtin_bit_cast(int, __builtin_amdgcn_cvt_pkrtz(a, b));
}

// ------------------------------------------------------------------
// fp32 -> fp16 convert, 8 elems/thread
// ------------------------------------------------------------------
__global__ __launch_bounds__(256) void cvt_f32_f16(const float* __restrict__ src,
                                                   _Float16* __restrict__ dst, int n8) {
  int i = blockIdx.x * 256 + threadIdx.x;
  if (i >= n8) return;
  const float4* s4 = (const float4*)src;
  float4 a = s4[2 * (size_t)i];
  float4 b = s4[2 * (size_t)i + 1];
  half8 h;
  h[0] = (_Float16)a.x; h[1] = (_Float16)a.y; h[2] = (_Float16)a.z; h[3] = (_Float16)a.w;
  h[4] = (_Float16)b.x; h[5] = (_Float16)b.y; h[6] = (_Float16)b.z; h[7] = (_Float16)b.w;
  *(half8*)(dst + 8 * (size_t)i) = h;
}

// ------------------------------------------------------------------
// NT GEMM: 128x256 tile, BK=32, 8 waves (2Mx4N, per-wave 64x64 = acc[4][4]).
// 6-slot LDS ring, stage t+4 during t. ONE barrier per tile (end), counted
// vmcnt ladder 9/6/3/0. NO mid-tile barrier: waves skew so the DS pipe
// (ds_read_b128) and MFMA pipe overlap across waves instead of serializing.
// ------------------------------------------------------------------
__global__ __launch_bounds__(512) void gemm_nt(
    const _Float16* __restrict__ A, const _Float16* __restrict__ W,
    const float* __restrict__ bias, float* __restrict__ C,
    int M, int N, int K, int kdepth, int mode,
    _Float16* __restrict__ qfp, _Float16* __restrict__ kfp, _Float16* __restrict__ vfp) {
  __shared__ __align__(16) _Float16 lds[73728];
  const int tid = threadIdx.x;
  const int w = tid >> 6, lane = tid & 63;
  const int wm = w >> 2, wn = w & 3;
  const int g = lane >> 4, r16 = lane & 15;
  const int gx = gridDim.x;  // N tiles
  const int gy = gridDim.y;  // M tiles
  const int nwg = gx * gy;
  const int flat = blockIdx.y * gx + blockIdx.x;
  const int c = (flat & 7) * (nwg >> 3) + (flat >> 3);  // XCD-chunked id (nwg%8==0)
  const int tm = c % gy, tn = c / gy;                   // tm FAST: B-panel locality
  const int m0 = tm * 128, n0 = tn * 256;
  const int z = blockIdx.z;
  const _Float16* Az = A + (size_t)z * kdepth;
  const _Float16* Wz = W + (size_t)z * kdepth;
  const int NT = kdepth >> 5;

  const int sr = tid >> 2, sc = tid & 3;
  const int scA = ((sc ^ ((sr >> 1) & 3)) << 3);
  const int srB1 = 128 + sr;
  const int scB1 = ((sc ^ ((srB1 >> 1) & 3)) << 3);
  const _Float16* pa = Az + (size_t)(m0 + sr) * K + scA;
  const _Float16* pb0 = Wz + (size_t)(n0 + sr) * K + scA;
  const _Float16* pb1 = Wz + (size_t)(n0 + srB1) * K + scB1;
  const int wbase = w * 512;

#define STAGE(t_, slot_)                                   \
  {                                                        \
    const int ko_ = (t_) << 5;                             \
    const int sb_ = (slot_)*12288;                         \
    GLDS16(pa + ko_, &lds[sb_ + wbase]);                   \
    GLDS16(pb0 + ko_, &lds[sb_ + 4096 + wbase]);           \
    GLDS16(pb1 + ko_, &lds[sb_ + 8192 + wbase]);           \
  }

  floatx4 acc[4][4] = {};

  STAGE(0, 0);
  STAGE(1, 1);
  STAGE(2, 2);
  STAGE(3, 3);
  asm volatile("s_waitcnt vmcnt(9)" ::: "memory");
  __builtin_amdgcn_s_barrier();
  __builtin_amdgcn_sched_barrier(0);

  const int swzsel = (r16 >> 1) & 3;
  int sC = 0, sS = 4;
  for (int t = 0; t < NT; ++t) {
    if (t + 4 < NT) STAGE(t + 4, sS);
    const int ab = sC * 12288, bb = ab + 4096;
    half8 af[4], bf[4];
#pragma unroll
    for (int fm = 0; fm < 4; ++fm) {
      int arow = wm * 64 + fm * 16 + r16;
      af[fm] = *(const half8*)&lds[ab + arow * 32 + ((g ^ swzsel) << 3)];
    }
#pragma unroll
    for (int fn = 0; fn < 4; ++fn) {
      int brow = wn * 64 + fn * 16 + r16;
      bf[fn] = *(const half8*)&lds[bb + brow * 32 + ((g ^ swzsel) << 3)];
    }
    // no mid-tile barrier: waves skew; DS and MFMA pipes overlap across waves
    __builtin_amdgcn_s_setprio(1);
#pragma unroll
    for (int fm = 0; fm < 4; ++fm)
#pragma unroll
      for (int fn = 0; fn < 4; ++fn)
        acc[fm][fn] = MFMA16(af[fm], bf[fn], acc[fm][fn]);
    __builtin_amdgcn_s_setprio(0);
    {
      const int r = NT - 1 - t;
      if (r >= 4)
        asm volatile("s_waitcnt vmcnt(9)" ::: "memory");
      else if (r == 3)
        asm volatile("s_waitcnt vmcnt(6)" ::: "memory");
      else if (r == 2)
        asm volatile("s_waitcnt vmcnt(3)" ::: "memory");
      else if (r == 1)
        asm volatile("s_waitcnt vmcnt(0)" ::: "memory");
    }
    __builtin_amdgcn_sched_barrier(0);
    __builtin_amdgcn_s_barrier();
    if (++sC == 6) sC = 0;
    if (++sS == 6) sS = 0;
  }
#undef STAGE

  if (mode == 1) {
    const int gc = (n0 + wn * 64) >> 7;
    const int h = gc / 3, s = gc - 3 * h;
    _Float16* dst = (s == 0) ? qfp : (s == 1 ? kfp : vfp);
    const float theta = exp2f(-(float)r16 * 0.83048202372184058f);
    const bool dorope = (s < 2) && ((wn & 1) == 0);
#pragma unroll
    for (int fm = 0; fm < 4; ++fm)
#pragma unroll
      for (int ri = 0; ri < 4; ++ri) {
        int tt = m0 + wm * 64 + fm * 16 + g * 4 + ri;
        float v[4];
#pragma unroll
        for (int j = 0; j < 4; ++j)
          v[j] = acc[fm][j][ri] + bias[n0 + wn * 64 + j * 16 + r16];
        if (dorope) {
          float sn, cs;
          sincosf((float)tt * theta, &sn, &cs);
          float a0 = v[0], a1 = v[1];
          v[0] = a0 * cs - a1 * sn;
          v[1] = a1 * cs + a0 * sn;
        }
        if (s == 0) {
#pragma unroll
          for (int j = 0; j < 4; ++j) v[j] *= 0.12751744f;  // 1/sqrt(128)*log2(e)
        }
        size_t rb = ((size_t)h * 2048 + tt) * 128 + (wn & 1) * 64 + r16;
#pragma unroll
        for (int j = 0; j < 4; ++j) dst[rb + j * 16] = (_Float16)v[j];
      }
  } else {
    float* Cz = C + (size_t)z * M * N;
#pragma unroll
    for (int fm = 0; fm < 4; ++fm)
#pragma unroll
      for (int ri = 0; ri < 4; ++ri) {
        int row = m0 + wm * 64 + fm * 16 + g * 4 + ri;
#pragma unroll
        for (int j = 0; j < 4; ++j) {
          int col = n0 + wn * 64 + j * 16 + r16;
          float v = acc[fm][j][ri];
          if (mode == 0) v += bias[col];
          Cz[(size_t)row * N + col] = v;
        }
      }
  }
}

// ------------------------------------------------------------------
// out = p0 + p1 + bias (split-K combine), float4-vectorized
// ------------------------------------------------------------------
__global__ __launch_bounds__(256) void add_bias(const float* __restrict__ p0,
                                                const float* __restrict__ p1,
                                                const float* __restrict__ bias,
                                                float* __restrict__ out) {
  int i = blockIdx.x * 256 + threadIdx.x;
  float4 a = ((const float4*)p0)[i];
  float4 b = ((const float4*)p1)[i];
  float4 bi = ((const float4*)bias)[i & 1023];
  float4 o;
  o.x = a.x + b.x + bi.x;
  o.y = a.y + b.y + bi.y;
  o.z = a.z + b.z + bi.z;
  o.w = a.w + b.w + bi.w;
  ((float4*)out)[i] = o;
}

// ------------------------------------------------------------------
// V [H][T][D] f16 -> V^T [H][D][T] f16, 64x64 tiles through LDS.
// ------------------------------------------------------------------
__global__ __launch_bounds__(256) void transpose_v(const _Float16* __restrict__ src,
                                                   _Float16* __restrict__ dst) {
  __shared__ __align__(16) _Float16 tile[64][72];
  const int h = blockIdx.z, tb = blockIdx.y, db = blockIdx.x;
  const int t0 = tb * 64, d0 = db * 64;
  const int r = threadIdx.x >> 2, a = threadIdx.x & 3;
  const _Float16* s = src + ((size_t)h * 2048 + t0 + r) * 128 + d0 + a * 16;
  *(half8*)&tile[r][a * 16] = *(const half8*)s;
  *(half8*)&tile[r][a * 16 + 8] = *(const half8*)(s + 8);
  __syncthreads();
  half8 o0, o1;
#pragma unroll
  for (int e = 0; e < 8; ++e) o0[e] = tile[a * 16 + e][r];
#pragma unroll
  for (int e = 0; e < 8; ++e) o1[e] = tile[a * 16 + 8 + e][r];
  _Float16* dp = dst + ((size_t)h * 128 + d0 + r) * 2048 + t0 + a * 16;
  *(half8*)dp = o0;
  *(half8*)(dp + 8) = o1;
}

// ------------------------------------------------------------------
// Flash attention, causal. 512 blocks, 4 waves x 32 q-rows, KVBLK=64,
// K/V in 2-slot LDS ring. NEW vs R5:
//  - ASTAGE issues 4 K-loads then 4 V-loads; end-of-tile waits vmcnt(4)
//    (K ready, V still in flight); second counted vmcnt(8) + barrier after
//    softmax hides the V drain under softmax/P-transpose work.
//  - P-redistribute via per-wave LDS scratch (144B row pitch, bank-uniform):
//    8 pk2 + 4 ds_write_b64 + 2 ds_read_b128 per frag-row, replacing
//    32 ds_bpermute + 16 selects (DS-pipe pressure cut ~40%).
// ------------------------------------------------------------------
__global__ __launch_bounds__(256, 2) void attn(const _Float16* __restrict__ qf,
                                               const _Float16* __restrict__ kf,
                                               const _Float16* __restrict__ vt,
                                               _Float16* __restrict__ yf) {
  // K: 2x8192 halfs, V: 2x8192 at +16384, P-scratch: 4 waves x 1152 at +32768
  __shared__ __align__(16) _Float16 SL[37376];
  const int bid = blockIdx.x;
  const int halfsel = bid >> 8, idx = bid & 255;
  const int h = idx & 31, qb = idx >> 5;
  const int qt = halfsel ? qb : 15 - qb;
  const int lane = threadIdx.x & 63, wave = threadIdx.x >> 6;
  const int g = lane >> 4, r16 = lane & 15;
  const int q0 = qt * 128 + wave * 32;
  const _Float16* qh = qf + (size_t)h * (2048 * 128);
  const _Float16* kh = kf + (size_t)h * (2048 * 128);
  const _Float16* vh = vt + (size_t)h * (128 * 2048);

  half8 qfr[2][4];
#pragma unroll
  for (int i = 0; i < 2; ++i)
#pragma unroll
    for (int kk = 0; kk < 4; ++kk)
      qfr[i][kk] = *(const half8*)(qh + (size_t)(q0 + i * 16 + r16) * 128 + kk * 32 + g * 8);

  floatx4 O[8][2] = {};
  float m[2] = {-1e30f, -1e30f}, l[2] = {0.f, 0.f};
  const int nkt = 2 * qt + 2;

  const int l4 = lane >> 4, l15 = lane & 15, l3v = lane >> 3, l7 = lane & 7;
  const int prow = 32768 + wave * 1152 + r16 * 72;  // P-scratch row (halfs)

  // K loads first, then V loads (vmcnt(4) at tile end waits only on K)
#define ASTAGE(kt_)                                                                          \
  {                                                                                          \
    const int sl_ = (kt_) & 1;                                                               \
    const int k0_ = (kt_) * 64;                                                              \
    _Float16* kb_ = &SL[sl_ * 8192 + wave * 2048];                                           \
    _Float16* vb_ = &SL[16384 + sl_ * 8192 + wave * 2048];                                   \
    _Pragma("unroll") for (int j_ = 0; j_ < 4; ++j_) {                                       \
      const int krow_ = 16 * wave + 4 * j_ + l4;                                             \
      GLDS16(kh + (size_t)(k0_ + krow_) * 128 + ((l15 ^ (krow_ & 7)) << 3), kb_ + j_ * 512); \
    }                                                                                        \
    _Pragma("unroll") for (int j_ = 0; j_ < 4; ++j_) {                                       \
      const int vrow_ = 32 * wave + 8 * j_ + l3v;                                            \
      GLDS16(vh + (size_t)vrow_ * 2048 + k0_ + ((l7 ^ l3v) << 3), vb_ + j_ * 512);           \
    }                                                                                        \
  }

  ASTAGE(0);
  asm volatile("s_waitcnt vmcnt(0)" ::: "memory");
  __builtin_amdgcn_s_barrier();
  __builtin_amdgcn_sched_barrier(0);

  const int kswz = r16 & 7;
  for (int kt = 0; kt < nkt; ++kt) {
    const int slot = kt & 1;
    const int k0 = kt * 64;
    if (kt + 1 < nkt) ASTAGE(kt + 1);

    // --- S^T = K @ Q from LDS K tile ---
    floatx4 S[4][2] = {};
    const int kbase = slot * 8192;
#pragma unroll
    for (int j = 0; j < 4; ++j) {
      const int rb = kbase + (j * 16 + r16) * 128;
      half8 kf0 = *(const half8*)&SL[rb + (((0 + g) ^ kswz) << 3)];
      half8 kf1 = *(const half8*)&SL[rb + (((4 + g) ^ kswz) << 3)];
      half8 kf2 = *(const half8*)&SL[rb + (((8 + g) ^ kswz) << 3)];
      half8 kf3 = *(const half8*)&SL[rb + (((12 + g) ^ kswz) << 3)];
      S[j][0] = MFMA16(kf0, qfr[0][0], S[j][0]);
      S[j][1] = MFMA16(kf0, qfr[1][0], S[j][1]);
      S[j][0] = MFMA16(kf1, qfr[0][1], S[j][0]);
      S[j][1] = MFMA16(kf1, qfr[1][1], S[j][1]);
      S[j][0] = MFMA16(kf2, qfr[0][2], S[j][0]);
      S[j][1] = MFMA16(kf2, qfr[1][2], S[j][1]);
      S[j][0] = MFMA16(kf3, qfr[0][3], S[j][0]);
      S[j][1] = MFMA16(kf3, qfr[1][3], S[j][1]);
    }

    if (kt >= 2 * qt) {
#pragma unroll
      for (int j = 0; j < 4; ++j)
#pragma unroll
        for (int r = 0; r < 4; ++r) {
          int key = k0 + j * 16 + g * 4 + r;
#pragma unroll
          for (int i = 0; i < 2; ++i)
            if (key > q0 + i * 16 + r16) S[j][i][r] = -1e30f;
        }
    }

    float rm[2];
#pragma unroll
    for (int i = 0; i < 2; ++i) {
      float a0 = fmaxf(fmaxf(S[0][i][0], S[0][i][1]), fmaxf(S[0][i][2], S[0][i][3]));
      float a1 = fmaxf(fmaxf(S[1][i][0], S[1][i][1]), fmaxf(S[1][i][2], S[1][i][3]));
      float a2 = fmaxf(fmaxf(S[2][i][0], S[2][i][1]), fmaxf(S[2][i][2], S[2][i][3]));
      float a3 = fmaxf(fmaxf(S[3][i][0], S[3][i][1]), fmaxf(S[3][i][2], S[3][i][3]));
      float a = fmaxf(fmaxf(a0, a1), fmaxf(a2, a3));
      a = fmaxf(a, __shfl_xor(a, 16));
      a = fmaxf(a, __shfl_xor(a, 32));
      rm[i] = a;
    }

    if (__any((rm[0] > m[0] + 2.0f) || (rm[1] > m[1] + 2.0f))) {
#pragma unroll
      for (int i = 0; i < 2; ++i) {
        float mn = fmaxf(m[i], rm[i]);
        float corr = fast_exp2(m[i] - mn);
        m[i] = mn;
        l[i] *= corr;
#pragma unroll
        for (int n = 0; n < 8; ++n) O[n][i] = O[n][i] * corr;
      }
    }

#pragma unroll
    for (int i = 0; i < 2; ++i) {
      float s = 0.f;
#pragma unroll
      for (int j = 0; j < 4; ++j)
#pragma unroll
        for (int r = 0; r < 4; ++r) {
          float p = fast_exp2(S[j][i][r] - m[i]);
          S[j][i][r] = p;
          s += p;
        }
      s += __shfl_xor(s, 16);
      s += __shfl_xor(s, 32);
      l[i] += s;
    }

    // --- P-transpose via per-wave LDS scratch (serialize i to reuse 16 rows) ---
    half8 pba[2], pbb[2];
    {
#pragma unroll
      for (int j = 0; j < 4; ++j) {
        uint2 wv2;
        wv2.x = (unsigned)pk2(S[j][0][0], S[j][0][1]);
        wv2.y = (unsigned)pk2(S[j][0][2], S[j][0][3]);
        *(uint2*)&SL[prow + j * 16 + g * 4] = wv2;
      }
      pba[0] = *(const half8*)&SL[prow + g * 8];
      pba[1] = *(const half8*)&SL[prow + 32 + g * 8];
#pragma unroll
      for (int j = 0; j < 4; ++j) {
        uint2 wv2;
        wv2.x = (unsigned)pk2(S[j][1][0], S[j][1][1]);
        wv2.y = (unsigned)pk2(S[j][1][2], S[j][1][3]);
        *(uint2*)&SL[prow + j * 16 + g * 4] = wv2;
      }
      pbb[0] = *(const half8*)&SL[prow + g * 8];
      pbb[1] = *(const half8*)&SL[prow + 32 + g * 8];
    }

    // --- V-ready wait (counted; V drain hidden under the softmax above) ---
    if (kt + 1 < nkt)
      asm volatile("s_waitcnt vmcnt(8)" ::: "memory");
    else
      asm volatile("s_waitcnt vmcnt(0)" ::: "memory");
    __builtin_amdgcn_sched_barrier(0);
    __builtin_amdgcn_s_barrier();

    // --- O^T += V^T @ P^T from LDS V tile ---
    const int vbase = 16384 + slot * 8192;
#pragma unroll
    for (int cc = 0; cc < 2; ++cc) {
#pragma unroll
      for (int n = 0; n < 8; ++n) {
        half8 va = *(const half8*)&SL[vbase + (n * 16 + r16) * 64 + ((((cc << 2) + g) ^ kswz) << 3)];
        O[n][0] = MFMA16(va, (cc == 0) ? pba[0] : pba[1], O[n][0]);
        O[n][1] = MFMA16(va, (cc == 0) ? pbb[0] : pbb[1], O[n][1]);
      }
    }

    // --- K-ready wait for next tile (V of next tile stays in flight) ---
    if (kt + 1 < nkt) {
      asm volatile("s_waitcnt vmcnt(4)" ::: "memory");
      __builtin_amdgcn_sched_barrier(0);
      __builtin_amdgcn_s_barrier();
    }
  }
#undef ASTAGE

#pragma unroll
  for (int i = 0; i < 2; ++i) {
    float inv = 1.0f / l[i];
    size_t rb = (size_t)(q0 + i * 16 + r16) * 4096 + h * 128 + g * 4;
#pragma unroll
    for (int n = 0; n < 8; ++n) {
      half4v o;
      o[0] = (_Float16)(O[n][i][0] * inv);
      o[1] = (_Float16)(O[n][i][1] * inv);
      o[2] = (_Float16)(O[n][i][2] * inv);
      o[3] = (_Float16)(O[n][i][3] * inv);
      *(half4v*)(yf + rb + n * 16) = o;
    }
  }
}

// ------------------------------------------------------------------
extern "C" void kernel_launch(void* const* d_in, const int* in_sizes, int n_in,
                              void* d_out, int out_size, void* d_ws, size_t ws_size,
                              hipStream_t stream) {
  const float* x = (const float*)d_in[0];
  const float* w_attn = (const float*)d_in[1];
  const float* b_attn = (const float*)d_in[2];
  const float* w_proj = (const float*)d_in[3];
  const float* b_proj = (const float*)d_in[4];
  float* out = (float*)d_out;

  _Float16* xh = (_Float16*)d_ws;
  _Float16* wa = xh + (size_t)2048 * 4096;
  _Float16* wp = wa + (size_t)12288 * 4096;
  _Float16* qfp = wp + (size_t)4096 * 4096;
  _Float16* kfp = qfp + (size_t)32 * 2048 * 128;
  _Float16* vfp = kfp + (size_t)32 * 2048 * 128;
  _Float16* yf = vfp + (size_t)32 * 2048 * 128;
  _Float16* vtp = xh;      // alias: xh dead after qkv GEMM
  float* pK = (float*)wa;  // alias: wa dead after qkv GEMM

  cvt_f32_f16<<<(2048 * 4096 / 8 + 255) / 256, 256, 0, stream>>>(x, xh, 2048 * 4096 / 8);
  cvt_f32_f16<<<(12288 * 4096 / 8 + 255) / 256, 256, 0, stream>>>(w_attn, wa, 12288 * 4096 / 8);
  cvt_f32_f16<<<(4096 * 4096 / 8 + 255) / 256, 256, 0, stream>>>(w_proj, wp, 4096 * 4096 / 8);

  gemm_nt<<<dim3(48, 16, 1), 512, 0, stream>>>(xh, wa, b_attn, nullptr, 2048, 12288, 4096,
                                               4096, 1, qfp, kfp, vfp);
  transpose_v<<<dim3(2, 32, 32), 256, 0, stream>>>(vfp, vtp);
  attn<<<512, 256, 0, stream>>>(qfp, kfp, vtp, yf);
  gemm_nt<<<dim3(16, 16, 2), 512, 0, stream>>>(yf, wp, nullptr, pK, 2048, 4096, 4096,
                                               2048, 2, nullptr, nullptr, nullptr);
  add_bias<<<2048 * 4096 / 4 / 256, 256, 0, stream>>>(pK, pK + (size_t)2048 * 4096, b_proj, out);
}

// Round 7
// 744.053 us; speedup vs baseline: 1.2217x; 1.0289x over previous
//
#include <hip/hip_runtime.h>

typedef _Float16 half8 __attribute__((ext_vector_type(8)));
typedef _Float16 half4v __attribute__((ext_vector_type(4)));
typedef float floatx4 __attribute__((ext_vector_type(4)));
typedef unsigned int uintx4 __attribute__((ext_vector_type(4)));

#define GLDS16(gsrc, ldst)                                                                  \
  __builtin_amdgcn_global_load_lds((const __attribute__((address_space(1))) void*)(gsrc),   \
                                   (__attribute__((address_space(3))) void*)(ldst), 16, 0, 0)
#define MFMA16(a, b, c) __builtin_amdgcn_mfma_f32_16x16x32_f16(a, b, c, 0, 0, 0)

static __device__ __forceinline__ float fast_exp2(float x) {
#if __has_builtin(__builtin_amdgcn_exp2f)
  return __builtin_amdgcn_exp2f(x);
#else
  return exp2f(x);
#endif
}
static __device__ __forceinline__ int pk2(float a, float b) {
  return __builtin_bit_cast(int, __builtin_amdgcn_cvt_pkrtz(a, b));
}

// ------------------------------------------------------------------
// fp32 -> fp16 convert, 8 elems/thread
// ------------------------------------------------------------------
__global__ __launch_bounds__(256) void cvt_f32_f16(const float* __restrict__ src,
                                                   _Float16* __restrict__ dst, int n8) {
  int i = blockIdx.x * 256 + threadIdx.x;
  if (i >= n8) return;
  const float4* s4 = (const float4*)src;
  float4 a = s4[2 * (size_t)i];
  float4 b = s4[2 * (size_t)i + 1];
  half8 h;
  h[0] = (_Float16)a.x; h[1] = (_Float16)a.y; h[2] = (_Float16)a.z; h[3] = (_Float16)a.w;
  h[4] = (_Float16)b.x; h[5] = (_Float16)b.y; h[6] = (_Float16)b.z; h[7] = (_Float16)b.w;
  *(half8*)(dst + 8 * (size_t)i) = h;
}

// ------------------------------------------------------------------
// NT GEMM: 128x256 tile, BK=32, 8 waves (2Mx4N, per-wave 64x64 = acc[4][4]).
// 3-slot LDS ring (72KB) -> TWO blocks/CU: one block's DS-read storm overlaps
// the other's MFMA phase (R6 falsified intra-block overlap; the CU-shared DS
// pipe needs a co-resident partner). Stage t+2 during t; counted vmcnt(3)
// ladder (never 0 mid-loop); slot (t+2)%3 last read in tile t-1 -> race-free.
// ------------------------------------------------------------------
__global__ __launch_bounds__(512, 4) void gemm_nt(
    const _Float16* __restrict__ A, const _Float16* __restrict__ W,
    const float* __restrict__ bias, float* __restrict__ C,
    int M, int N, int K, int kdepth, int mode,
    _Float16* __restrict__ qfp, _Float16* __restrict__ kfp, _Float16* __restrict__ vfp) {
  __shared__ __align__(16) _Float16 lds[36864];  // 3 slots x (A 4096 + B 8192) halfs
  const int tid = threadIdx.x;
  const int w = tid >> 6, lane = tid & 63;
  const int wm = w >> 2, wn = w & 3;
  const int g = lane >> 4, r16 = lane & 15;
  const int gx = gridDim.x;  // N tiles
  const int gy = gridDim.y;  // M tiles
  const int nwg = gx * gy;
  const int flat = blockIdx.y * gx + blockIdx.x;
  const int c = (flat & 7) * (nwg >> 3) + (flat >> 3);  // XCD-chunked id (nwg%8==0)
  const int tm = c % gy, tn = c / gy;                   // tm FAST: B-panel locality
  const int m0 = tm * 128, n0 = tn * 256;
  const int z = blockIdx.z;
  const _Float16* Az = A + (size_t)z * kdepth;
  const _Float16* Wz = W + (size_t)z * kdepth;
  const int NT = kdepth >> 5;

  const int sr = tid >> 2, sc = tid & 3;
  const int scA = ((sc ^ ((sr >> 1) & 3)) << 3);
  const int srB1 = 128 + sr;
  const int scB1 = ((sc ^ ((srB1 >> 1) & 3)) << 3);
  const _Float16* pa = Az + (size_t)(m0 + sr) * K + scA;
  const _Float16* pb0 = Wz + (size_t)(n0 + sr) * K + scA;
  const _Float16* pb1 = Wz + (size_t)(n0 + srB1) * K + scB1;
  const int wbase = w * 512;

#define STAGE(t_, slot_)                                   \
  {                                                        \
    const int ko_ = (t_) << 5;                             \
    const int sb_ = (slot_)*12288;                         \
    GLDS16(pa + ko_, &lds[sb_ + wbase]);                   \
    GLDS16(pb0 + ko_, &lds[sb_ + 4096 + wbase]);           \
    GLDS16(pb1 + ko_, &lds[sb_ + 8192 + wbase]);           \
  }

  floatx4 acc[4][4] = {};

  STAGE(0, 0);
  STAGE(1, 1);
  asm volatile("s_waitcnt vmcnt(3)" ::: "memory");
  __builtin_amdgcn_s_barrier();
  __builtin_amdgcn_sched_barrier(0);

  const int swzsel = (r16 >> 1) & 3;
  int sC = 0, sS = 2;  // ring slots for tile t and t+2
  for (int t = 0; t < NT; ++t) {
    if (t + 2 < NT) STAGE(t + 2, sS);
    const int ab = sC * 12288, bb = ab + 4096;
    half8 af[4], bf[4];
#pragma unroll
    for (int fm = 0; fm < 4; ++fm) {
      int arow = wm * 64 + fm * 16 + r16;
      af[fm] = *(const half8*)&lds[ab + arow * 32 + ((g ^ swzsel) << 3)];
    }
#pragma unroll
    for (int fn = 0; fn < 4; ++fn) {
      int brow = wn * 64 + fn * 16 + r16;
      bf[fn] = *(const half8*)&lds[bb + brow * 32 + ((g ^ swzsel) << 3)];
    }
    __builtin_amdgcn_s_setprio(1);
#pragma unroll
    for (int fm = 0; fm < 4; ++fm)
#pragma unroll
      for (int fn = 0; fn < 4; ++fn)
        acc[fm][fn] = MFMA16(af[fm], bf[fn], acc[fm][fn]);
    __builtin_amdgcn_s_setprio(0);
    {
      const int r = NT - 1 - t;
      if (r >= 2) {
        asm volatile("s_waitcnt vmcnt(3)" ::: "memory");
        __builtin_amdgcn_sched_barrier(0);
        __builtin_amdgcn_s_barrier();
      } else if (r == 1) {
        asm volatile("s_waitcnt vmcnt(0)" ::: "memory");
        __builtin_amdgcn_sched_barrier(0);
        __builtin_amdgcn_s_barrier();
      }
      // r == 0: last tile, no further LDS consumers -> no wait/barrier
    }
    if (++sC == 3) sC = 0;
    if (++sS == 3) sS = 0;
  }
#undef STAGE

  if (mode == 1) {
    const int gc = (n0 + wn * 64) >> 7;
    const int h = gc / 3, s = gc - 3 * h;
    _Float16* dst = (s == 0) ? qfp : (s == 1 ? kfp : vfp);
    const float theta = exp2f(-(float)r16 * 0.83048202372184058f);
    const bool dorope = (s < 2) && ((wn & 1) == 0);
#pragma unroll
    for (int fm = 0; fm < 4; ++fm)
#pragma unroll
      for (int ri = 0; ri < 4; ++ri) {
        int tt = m0 + wm * 64 + fm * 16 + g * 4 + ri;
        float v[4];
#pragma unroll
        for (int j = 0; j < 4; ++j)
          v[j] = acc[fm][j][ri] + bias[n0 + wn * 64 + j * 16 + r16];
        if (dorope) {
          float sn, cs;
          sincosf((float)tt * theta, &sn, &cs);
          float a0 = v[0], a1 = v[1];
          v[0] = a0 * cs - a1 * sn;
          v[1] = a1 * cs + a0 * sn;
        }
        if (s == 0) {
#pragma unroll
          for (int j = 0; j < 4; ++j) v[j] *= 0.12751744f;  // 1/sqrt(128)*log2(e)
        }
        size_t rb = ((size_t)h * 2048 + tt) * 128 + (wn & 1) * 64 + r16;
#pragma unroll
        for (int j = 0; j < 4; ++j) dst[rb + j * 16] = (_Float16)v[j];
      }
  } else {
    float* Cz = C + (size_t)z * M * N;
#pragma unroll
    for (int fm = 0; fm < 4; ++fm)
#pragma unroll
      for (int ri = 0; ri < 4; ++ri) {
        int row = m0 + wm * 64 + fm * 16 + g * 4 + ri;
#pragma unroll
        for (int j = 0; j < 4; ++j) {
          int col = n0 + wn * 64 + j * 16 + r16;
          float v = acc[fm][j][ri];
          if (mode == 0) v += bias[col];
          Cz[(size_t)row * N + col] = v;
        }
      }
  }
}

// ------------------------------------------------------------------
// out = p0 + p1 + bias (split-K combine), float4-vectorized
// ------------------------------------------------------------------
__global__ __launch_bounds__(256) void add_bias(const float* __restrict__ p0,
                                                const float* __restrict__ p1,
                                                const float* __restrict__ bias,
                                                float* __restrict__ out) {
  int i = blockIdx.x * 256 + threadIdx.x;
  float4 a = ((const float4*)p0)[i];
  float4 b = ((const float4*)p1)[i];
  float4 bi = ((const float4*)bias)[i & 1023];
  float4 o;
  o.x = a.x + b.x + bi.x;
  o.y = a.y + b.y + bi.y;
  o.z = a.z + b.z + bi.z;
  o.w = a.w + b.w + bi.w;
  ((float4*)out)[i] = o;
}

// ------------------------------------------------------------------
// V [H][T][D] f16 -> V^T [H][D][T] f16, 64x64 tiles through LDS.
// ------------------------------------------------------------------
__global__ __launch_bounds__(256) void transpose_v(const _Float16* __restrict__ src,
                                                   _Float16* __restrict__ dst) {
  __shared__ __align__(16) _Float16 tile[64][72];
  const int h = blockIdx.z, tb = blockIdx.y, db = blockIdx.x;
  const int t0 = tb * 64, d0 = db * 64;
  const int r = threadIdx.x >> 2, a = threadIdx.x & 3;
  const _Float16* s = src + ((size_t)h * 2048 + t0 + r) * 128 + d0 + a * 16;
  *(half8*)&tile[r][a * 16] = *(const half8*)s;
  *(half8*)&tile[r][a * 16 + 8] = *(const half8*)(s + 8);
  __syncthreads();
  half8 o0, o1;
#pragma unroll
  for (int e = 0; e < 8; ++e) o0[e] = tile[a * 16 + e][r];
#pragma unroll
  for (int e = 0; e < 8; ++e) o1[e] = tile[a * 16 + 8 + e][r];
  _Float16* dp = dst + ((size_t)h * 128 + d0 + r) * 2048 + t0 + a * 16;
  *(half8*)dp = o0;
  *(half8*)(dp + 8) = o1;
}

// ------------------------------------------------------------------
// Flash attention, causal. 512 blocks, 4 waves x 32 q-rows, KVBLK=64,
// K/V in 2-slot LDS ring, 2 blocks/CU. NEW vs R6: ONE wait+barrier per tile
// (end-of-tile vmcnt(0)+barrier guarantees next tile's K AND V staged; the
// drain hides under the ~4000-cyc tile). Removes the mid-tile V-wait barrier
// from the serial chain.
// ------------------------------------------------------------------
__global__ __launch_bounds__(256, 2) void attn(const _Float16* __restrict__ qf,
                                               const _Float16* __restrict__ kf,
                                               const _Float16* __restrict__ vt,
                                               _Float16* __restrict__ yf) {
  // K: 2x8192 halfs, V: 2x8192 at +16384, P-scratch: 4 waves x 1152 at +32768
  __shared__ __align__(16) _Float16 SL[37376];
  const int bid = blockIdx.x;
  const int halfsel = bid >> 8, idx = bid & 255;
  const int h = idx & 31, qb = idx >> 5;
  const int qt = halfsel ? qb : 15 - qb;
  const int lane = threadIdx.x & 63, wave = threadIdx.x >> 6;
  const int g = lane >> 4, r16 = lane & 15;
  const int q0 = qt * 128 + wave * 32;
  const _Float16* qh = qf + (size_t)h * (2048 * 128);
  const _Float16* kh = kf + (size_t)h * (2048 * 128);
  const _Float16* vh = vt + (size_t)h * (128 * 2048);

  half8 qfr[2][4];
#pragma unroll
  for (int i = 0; i < 2; ++i)
#pragma unroll
    for (int kk = 0; kk < 4; ++kk)
      qfr[i][kk] = *(const half8*)(qh + (size_t)(q0 + i * 16 + r16) * 128 + kk * 32 + g * 8);

  floatx4 O[8][2] = {};
  float m[2] = {-1e30f, -1e30f}, l[2] = {0.f, 0.f};
  const int nkt = 2 * qt + 2;

  const int l4 = lane >> 4, l15 = lane & 15, l3v = lane >> 3, l7 = lane & 7;
  const int prow = 32768 + wave * 1152 + r16 * 72;  // P-scratch row (halfs)

#define ASTAGE(kt_)                                                                          \
  {                                                                                          \
    const int sl_ = (kt_) & 1;                                                               \
    const int k0_ = (kt_) * 64;                                                              \
    _Float16* kb_ = &SL[sl_ * 8192 + wave * 2048];                                           \
    _Float16* vb_ = &SL[16384 + sl_ * 8192 + wave * 2048];                                   \
    _Pragma("unroll") for (int j_ = 0; j_ < 4; ++j_) {                                       \
      const int krow_ = 16 * wave + 4 * j_ + l4;                                             \
      GLDS16(kh + (size_t)(k0_ + krow_) * 128 + ((l15 ^ (krow_ & 7)) << 3), kb_ + j_ * 512); \
    }                                                                                        \
    _Pragma("unroll") for (int j_ = 0; j_ < 4; ++j_) {                                       \
      const int vrow_ = 32 * wave + 8 * j_ + l3v;                                            \
      GLDS16(vh + (size_t)vrow_ * 2048 + k0_ + ((l7 ^ l3v) << 3), vb_ + j_ * 512);           \
    }                                                                                        \
  }

  ASTAGE(0);
  asm volatile("s_waitcnt vmcnt(0)" ::: "memory");
  __builtin_amdgcn_s_barrier();
  __builtin_amdgcn_sched_barrier(0);

  const int kswz = r16 & 7;
  for (int kt = 0; kt < nkt; ++kt) {
    const int slot = kt & 1;
    const int k0 = kt * 64;
    if (kt + 1 < nkt) ASTAGE(kt + 1);

    // --- S^T = K @ Q from LDS K tile ---
    floatx4 S[4][2] = {};
    const int kbase = slot * 8192;
#pragma unroll
    for (int j = 0; j < 4; ++j) {
      const int rb = kbase + (j * 16 + r16) * 128;
      half8 kf0 = *(const half8*)&SL[rb + (((0 + g) ^ kswz) << 3)];
      half8 kf1 = *(const half8*)&SL[rb + (((4 + g) ^ kswz) << 3)];
      half8 kf2 = *(const half8*)&SL[rb + (((8 + g) ^ kswz) << 3)];
      half8 kf3 = *(const half8*)&SL[rb + (((12 + g) ^ kswz) << 3)];
      S[j][0] = MFMA16(kf0, qfr[0][0], S[j][0]);
      S[j][1] = MFMA16(kf0, qfr[1][0], S[j][1]);
      S[j][0] = MFMA16(kf1, qfr[0][1], S[j][0]);
      S[j][1] = MFMA16(kf1, qfr[1][1], S[j][1]);
      S[j][0] = MFMA16(kf2, qfr[0][2], S[j][0]);
      S[j][1] = MFMA16(kf2, qfr[1][2], S[j][1]);
      S[j][0] = MFMA16(kf3, qfr[0][3], S[j][0]);
      S[j][1] = MFMA16(kf3, qfr[1][3], S[j][1]);
    }

    if (kt >= 2 * qt) {
#pragma unroll
      for (int j = 0; j < 4; ++j)
#pragma unroll
        for (int r = 0; r < 4; ++r) {
          int key = k0 + j * 16 + g * 4 + r;
#pragma unroll
          for (int i = 0; i < 2; ++i)
            if (key > q0 + i * 16 + r16) S[j][i][r] = -1e30f;
        }
    }

    float rm[2];
#pragma unroll
    for (int i = 0; i < 2; ++i) {
      float a0 = fmaxf(fmaxf(S[0][i][0], S[0][i][1]), fmaxf(S[0][i][2], S[0][i][3]));
      float a1 = fmaxf(fmaxf(S[1][i][0], S[1][i][1]), fmaxf(S[1][i][2], S[1][i][3]));
      float a2 = fmaxf(fmaxf(S[2][i][0], S[2][i][1]), fmaxf(S[2][i][2], S[2][i][3]));
      float a3 = fmaxf(fmaxf(S[3][i][0], S[3][i][1]), fmaxf(S[3][i][2], S[3][i][3]));
      float a = fmaxf(fmaxf(a0, a1), fmaxf(a2, a3));
      a = fmaxf(a, __shfl_xor(a, 16));
      a = fmaxf(a, __shfl_xor(a, 32));
      rm[i] = a;
    }

    if (__any((rm[0] > m[0] + 2.0f) || (rm[1] > m[1] + 2.0f))) {
#pragma unroll
      for (int i = 0; i < 2; ++i) {
        float mn = fmaxf(m[i], rm[i]);
        float corr = fast_exp2(m[i] - mn);
        m[i] = mn;
        l[i] *= corr;
#pragma unroll
        for (int n = 0; n < 8; ++n) O[n][i] = O[n][i] * corr;
      }
    }

#pragma unroll
    for (int i = 0; i < 2; ++i) {
      float s = 0.f;
#pragma unroll
      for (int j = 0; j < 4; ++j)
#pragma unroll
        for (int r = 0; r < 4; ++r) {
          float p = fast_exp2(S[j][i][r] - m[i]);
          S[j][i][r] = p;
          s += p;
        }
      s += __shfl_xor(s, 16);
      s += __shfl_xor(s, 32);
      l[i] += s;
    }

    // --- P-transpose via per-wave LDS scratch ---
    half8 pba[2], pbb[2];
    {
#pragma unroll
      for (int j = 0; j < 4; ++j) {
        uint2 wv2;
        wv2.x = (unsigned)pk2(S[j][0][0], S[j][0][1]);
        wv2.y = (unsigned)pk2(S[j][0][2], S[j][0][3]);
        *(uint2*)&SL[prow + j * 16 + g * 4] = wv2;
      }
      pba[0] = *(const half8*)&SL[prow + g * 8];
      pba[1] = *(const half8*)&SL[prow + 32 + g * 8];
#pragma unroll
      for (int j = 0; j < 4; ++j) {
        uint2 wv2;
        wv2.x = (unsigned)pk2(S[j][1][0], S[j][1][1]);
        wv2.y = (unsigned)pk2(S[j][1][2], S[j][1][3]);
        *(uint2*)&SL[prow + j * 16 + g * 4] = wv2;
      }
      pbb[0] = *(const half8*)&SL[prow + g * 8];
      pbb[1] = *(const half8*)&SL[prow + 32 + g * 8];
    }

    // --- O^T += V^T @ P^T from LDS V tile (staged at end of previous tile) ---
    const int vbase = 16384 + slot * 8192;
#pragma unroll
    for (int cc = 0; cc < 2; ++cc) {
#pragma unroll
      for (int n = 0; n < 8; ++n) {
        half8 va = *(const half8*)&SL[vbase + (n * 16 + r16) * 64 + ((((cc << 2) + g) ^ kswz) << 3)];
        O[n][0] = MFMA16(va, (cc == 0) ? pba[0] : pba[1], O[n][0]);
        O[n][1] = MFMA16(va, (cc == 0) ? pbb[0] : pbb[1], O[n][1]);
      }
    }

    // --- single end-of-tile wait: next tile's K AND V staged ---
    if (kt + 1 < nkt) {
      asm volatile("s_waitcnt vmcnt(0)" ::: "memory");
      __builtin_amdgcn_sched_barrier(0);
      __builtin_amdgcn_s_barrier();
    }
  }
#undef ASTAGE

#pragma unroll
  for (int i = 0; i < 2; ++i) {
    float inv = 1.0f / l[i];
    size_t rb = (size_t)(q0 + i * 16 + r16) * 4096 + h * 128 + g * 4;
#pragma unroll
    for (int n = 0; n < 8; ++n) {
      half4v o;
      o[0] = (_Float16)(O[n][i][0] * inv);
      o[1] = (_Float16)(O[n][i][1] * inv);
      o[2] = (_Float16)(O[n][i][2] * inv);
      o[3] = (_Float16)(O[n][i][3] * inv);
      *(half4v*)(yf + rb + n * 16) = o;
    }
  }
}

// ------------------------------------------------------------------
extern "C" void kernel_launch(void* const* d_in, const int* in_sizes, int n_in,
                              void* d_out, int out_size, void* d_ws, size_t ws_size,
                              hipStream_t stream) {
  const float* x = (const float*)d_in[0];
  const float* w_attn = (const float*)d_in[1];
  const float* b_attn = (const float*)d_in[2];
  const float* w_proj = (const float*)d_in[3];
  const float* b_proj = (const float*)d_in[4];
  float* out = (float*)d_out;

  _Float16* xh = (_Float16*)d_ws;
  _Float16* wa = xh + (size_t)2048 * 4096;
  _Float16* wp = wa + (size_t)12288 * 4096;
  _Float16* qfp = wp + (size_t)4096 * 4096;
  _Float16* kfp = qfp + (size_t)32 * 2048 * 128;
  _Float16* vfp = kfp + (size_t)32 * 2048 * 128;
  _Float16* yf = vfp + (size_t)32 * 2048 * 128;
  _Float16* vtp = xh;      // alias: xh dead after qkv GEMM
  float* pK = (float*)wa;  // alias: wa dead after qkv GEMM

  cvt_f32_f16<<<(2048 * 4096 / 8 + 255) / 256, 256, 0, stream>>>(x, xh, 2048 * 4096 / 8);
  cvt_f32_f16<<<(12288 * 4096 / 8 + 255) / 256, 256, 0, stream>>>(w_attn, wa, 12288 * 4096 / 8);
  cvt_f32_f16<<<(4096 * 4096 / 8 + 255) / 256, 256, 0, stream>>>(w_proj, wp, 4096 * 4096 / 8);

  gemm_nt<<<dim3(48, 16, 1), 512, 0, stream>>>(xh, wa, b_attn, nullptr, 2048, 12288, 4096,
                                               4096, 1, qfp, kfp, vfp);
  transpose_v<<<dim3(2, 32, 32), 256, 0, stream>>>(vfp, vtp);
  attn<<<512, 256, 0, stream>>>(qfp, kfp, vtp, yf);
  gemm_nt<<<dim3(16, 16, 2), 512, 0, stream>>>(yf, wp, nullptr, pK, 2048, 4096, 4096,
                                               2048, 2, nullptr, nullptr, nullptr);
  add_bias<<<2048 * 4096 / 4 / 256, 256, 0, stream>>>(pK, pK + (size_t)2048 * 4096, b_proj, out);
}